// Round 7
// baseline (528.067 us; speedup 1.0000x reference)
//
#include <hip/hip_runtime.h>
#include <math.h>

#define NB 64          // graphs
#define N0 1024        // nodes per graph (stage 1)
#define NEDGE 1048576  // total edges
#define FIN 10
#define NCLS 10
#define KP1 205
#define KP2 41
#define KP3 9

static inline int ceil_div(int a, int b) { return (a + b - 1) / b; }

// ---------------- edge init (int2, fused degree count) ----------------
__global__ void init_edges_count_k(const int* __restrict__ ei, int2* __restrict__ eb,
                                   int* __restrict__ cnt) {
    int e = blockIdx.x * blockDim.x + threadIdx.x;
    if (e >= NEDGE) return;
    int2 ed; ed.x = ei[e]; ed.y = ei[NEDGE + e];
    eb[e] = ed;
    atomicAdd(&cnt[ed.y], 1);
}

// ---------------- CSR offsets: per-block scan + atomic block base ----------------
// Region ORDER across nodes is arbitrary — only disjointness matters for the gather.
__global__ void offsets_k(const int* __restrict__ cnt, int* __restrict__ off,
                          int* __restrict__ cursor, float* __restrict__ dis,
                          int* __restrict__ gctr, int n) {
    __shared__ int buf[256];
    __shared__ int base;
    int i = blockIdx.x * 256 + threadIdx.x;
    int v = (i < n) ? cnt[i] : 0;
    buf[threadIdx.x] = v;
    __syncthreads();
    #pragma unroll
    for (int s = 1; s < 256; s <<= 1) {
        int t = (threadIdx.x >= s) ? buf[threadIdx.x - s] : 0;
        __syncthreads();
        buf[threadIdx.x] += t;
        __syncthreads();
    }
    if (threadIdx.x == 255) base = atomicAdd(gctr, buf[255]);
    __syncthreads();
    if (i < n) {
        int excl = base + buf[threadIdx.x] - v;
        off[i] = excl;
        cursor[i] = excl;
        dis[i] = rsqrtf((float)v + 1.0f);
    }
}

// ---------------- scatter: csr2 = {src, dis[src]} ----------------
__global__ void scatter1_k(const int2* __restrict__ eb, int* __restrict__ cursor,
                           const float* __restrict__ dis, int2* __restrict__ csr2) {
    int e = blockIdx.x * blockDim.x + threadIdx.x;
    if (e >= NEDGE) return;
    int2 ed = eb[e];
    int p = atomicAdd(&cursor[ed.y], 1);
    int2 o; o.x = ed.x; o.y = __float_as_int(dis[ed.x]);
    csr2[p] = o;
}

__global__ void scatter_dyn_k(const int2* __restrict__ eb, const int* __restrict__ nct,
                              int* __restrict__ cursor, const float* __restrict__ dis,
                              int2* __restrict__ csr2) {
    int total = *nct;
    for (int e = blockIdx.x * blockDim.x + threadIdx.x; e < total; e += gridDim.x * blockDim.x) {
        int2 ed = eb[e];
        int p = atomicAdd(&cursor[ed.y], 1);
        int2 o; o.x = ed.x; o.y = __float_as_int(dis[ed.x]);
        csr2[p] = o;
    }
}

// ---------------- edge remap + COMPACT alive edges ----------------
__global__ void edge_compact1_k(const int2* __restrict__ ebin, const int* __restrict__ newid,
                                int2* __restrict__ ebout, int* __restrict__ cntN,
                                int* __restrict__ ectr) {
    int e = blockIdx.x * blockDim.x + threadIdx.x;
    if (e >= NEDGE) return;
    int2 ed = ebin[e];
    int ns = newid[ed.x], nd = newid[ed.y];
    if (ns < 0 || nd < 0) return;
    atomicAdd(&cntN[nd], 1);
    int p = atomicAdd(ectr, 1);
    int2 o; o.x = ns; o.y = nd;
    ebout[p] = o;
}

__global__ void edge_compact_dyn_k(const int2* __restrict__ ebin, const int* __restrict__ nct,
                                   const int* __restrict__ newid, int2* __restrict__ ebout,
                                   int* __restrict__ cntN, int* __restrict__ ectr) {
    int total = *nct;
    for (int e = blockIdx.x * blockDim.x + threadIdx.x; e < total; e += gridDim.x * blockDim.x) {
        int2 ed = ebin[e];
        int ns = newid[ed.x], nd = newid[ed.y];
        if (ns < 0 || nd < 0) continue;
        atomicAdd(&cntN[nd], 1);
        int p = atomicAdd(ectr, 1);
        int2 o; o.x = ns; o.y = nd;
        ebout[p] = o;
    }
}

// ---------------- stage-1: aggregate RAW x (10-dim) pre-GEMM, LDS-staged graph ----
// y_i = dis_i * sum_j x[s_j]*dis_sj + dis_i^2 * x_i     (10 floats per node)
__global__ __launch_bounds__(256) void agg10_k(const float* __restrict__ x,
                                               const int2* __restrict__ csr2,
                                               const int* __restrict__ off,
                                               const int* __restrict__ cnt,
                                               const float* __restrict__ dis,
                                               float* __restrict__ y) {
    __shared__ float xl[N0 * 11];  // rows padded to 11 floats (bank spread)
    int b = blockIdx.x >> 2, chunk = blockIdx.x & 3;
    const float* xg = x + (size_t)b * (N0 * FIN);
    for (int u = threadIdx.x; u < N0 * FIN; u += 256) {
        int r = u / FIN, c = u - r * FIN;
        xl[r * 11 + c] = xg[u];
    }
    __syncthreads();
    int li = chunk * 256 + threadIdx.x;
    int i  = b * N0 + li;
    int s0 = off[i], m = cnt[i];
    int base = b * N0;
    float acc[FIN];
    #pragma unroll
    for (int f = 0; f < FIN; ++f) acc[f] = 0.f;
    int j = 0;
    for (; j + 2 <= m; j += 2) {
        int2 e0 = csr2[s0 + j], e1 = csr2[s0 + j + 1];
        int sl0 = (e0.x - base) * 11, sl1 = (e1.x - base) * 11;
        float w0 = __int_as_float(e0.y), w1 = __int_as_float(e1.y);
        #pragma unroll
        for (int f = 0; f < FIN; ++f) acc[f] += xl[sl0 + f] * w0 + xl[sl1 + f] * w1;
    }
    if (j < m) {
        int2 e0 = csr2[s0 + j];
        int sl0 = (e0.x - base) * 11;
        float w0 = __int_as_float(e0.y);
        #pragma unroll
        for (int f = 0; f < FIN; ++f) acc[f] += xl[sl0 + f] * w0;
    }
    float di = dis[i], d2 = di * di;
    #pragma unroll
    for (int f = 0; f < FIN; ++f)
        y[(size_t)i * FIN + f] = di * acc[f] + d2 * xl[li * 11 + f];
}

// ---------------- fused: hout = relu(y@W + b); hs = hout@Wsc; hsd = hs*dis -------
__global__ void gemm_fin_fused_k(const float* __restrict__ y, const float* __restrict__ W,
                                 const float* __restrict__ bb, const float* __restrict__ Wsc,
                                 const float* __restrict__ dis,
                                 float* __restrict__ hout, float* __restrict__ hs,
                                 float* __restrict__ hsd, int n) {
    __shared__ float Ws[FIN * 128];
    __shared__ float Sc[128];
    for (int u = threadIdx.x; u < FIN * 128; u += 256) Ws[u] = W[u];
    if (threadIdx.x < 128) Sc[threadIdx.x] = Wsc[threadIdx.x];
    __syncthreads();
    int t = blockIdx.x * 256 + threadIdx.x;
    int i = t >> 6, lane = threadIdx.x & 63;
    if (i >= n) return;
    float a = (lane < FIN) ? y[(size_t)i * FIN + lane] : 0.f;
    const float2* W2 = (const float2*)Ws;
    float ax = bb[lane * 2], ay = bb[lane * 2 + 1];
    #pragma unroll
    for (int k = 0; k < FIN; ++k) {
        float ak = __shfl(a, k);
        float2 w = W2[k * 64 + lane];
        ax += ak * w.x; ay += ak * w.y;
    }
    ax = fmaxf(ax, 0.f); ay = fmaxf(ay, 0.f);
    float2 o; o.x = ax; o.y = ay;
    ((float2*)hout)[(size_t)i * 64 + lane] = o;
    float part = ax * Sc[lane * 2] + ay * Sc[lane * 2 + 1];
    #pragma unroll
    for (int sh = 32; sh >= 1; sh >>= 1) part += __shfl_xor(part, sh);
    if (lane == 0) { hs[i] = part; hsd[i] = part * dis[i]; }
}

// ---------------- GEMM (K=128): 64x64 tile, 4x4 per thread, register-tiled -----
__global__ __launch_bounds__(256) void gemm128_tiled_k(const float* __restrict__ A,
                                                       const float* __restrict__ W,
                                                       float* __restrict__ C, int n) {
    __shared__ float As[64][33];
    __shared__ float Wt[32][64];
    int tx = threadIdx.x & 15, ty = threadIdx.x >> 4;
    int r0 = blockIdx.x * 64;
    int c0 = blockIdx.y * 64;
    float4 acc0 = {0,0,0,0}, acc1 = {0,0,0,0}, acc2 = {0,0,0,0}, acc3 = {0,0,0,0};
    int u = threadIdx.x;
    for (int k0 = 0; k0 < 128; k0 += 32) {
        __syncthreads();
        {
            int rr = u >> 3, cc = (u & 7) * 4;
            #pragma unroll
            for (int h = 0; h < 2; ++h) {
                int r = rr + h * 32;
                float4 v = {0,0,0,0};
                if (r0 + r < n) v = *(const float4*)&A[(size_t)(r0 + r) * 128 + k0 + cc];
                As[r][cc] = v.x; As[r][cc+1] = v.y; As[r][cc+2] = v.z; As[r][cc+3] = v.w;
            }
        }
        {
            int kk = u >> 4, c = (u & 15) * 4;
            #pragma unroll
            for (int h = 0; h < 2; ++h) {
                float4 v = *(const float4*)&W[(size_t)(k0 + kk + h * 16) * 128 + c0 + c];
                *(float4*)&Wt[kk + h * 16][c] = v;
            }
        }
        __syncthreads();
        #pragma unroll
        for (int kk = 0; kk < 32; ++kk) {
            float4 wv = *(const float4*)&Wt[kk][tx * 4];
            float a0 = As[ty * 4 + 0][kk];
            float a1 = As[ty * 4 + 1][kk];
            float a2 = As[ty * 4 + 2][kk];
            float a3 = As[ty * 4 + 3][kk];
            acc0.x += a0 * wv.x; acc0.y += a0 * wv.y; acc0.z += a0 * wv.z; acc0.w += a0 * wv.w;
            acc1.x += a1 * wv.x; acc1.y += a1 * wv.y; acc1.z += a1 * wv.z; acc1.w += a1 * wv.w;
            acc2.x += a2 * wv.x; acc2.y += a2 * wv.y; acc2.z += a2 * wv.z; acc2.w += a2 * wv.w;
            acc3.x += a3 * wv.x; acc3.y += a3 * wv.y; acc3.z += a3 * wv.z; acc3.w += a3 * wv.w;
        }
    }
    int r = r0 + ty * 4;
    if (r + 0 < n) *(float4*)&C[(size_t)(r + 0) * 128 + c0 + tx * 4] = acc0;
    if (r + 1 < n) *(float4*)&C[(size_t)(r + 1) * 128 + c0 + tx * 4] = acc1;
    if (r + 2 < n) *(float4*)&C[(size_t)(r + 2) * 128 + c0 + tx * 4] = acc2;
    if (r + 3 < n) *(float4*)&C[(size_t)(r + 3) * 128 + c0 + tx * 4] = acc3;
}

// ---------- fused GCN aggregation (stages 2/3): wave-per-node, csr2, XCD-swizzled --
__global__ void gcn_agg_fused2_k(const float* __restrict__ hW, const int2* __restrict__ csr2,
                                 const int* __restrict__ off, const int* __restrict__ cnt,
                                 const float* __restrict__ dis, const float* __restrict__ bias,
                                 const float* __restrict__ Wsc,
                                 float* __restrict__ hout, float* __restrict__ hs,
                                 float* __restrict__ hsd, int n, int cpx) {
    int wg = ((blockIdx.x & 7) * cpx) + (blockIdx.x >> 3);
    int t = wg * blockDim.x + threadIdx.x;
    int i = t >> 6;              // one wave per node
    int lane = threadIdx.x & 63;
    if (i >= n) return;
    const float2* hW2 = (const float2*)hW;
    int s0 = off[i], e0 = s0 + cnt[i];
    float accx = 0.f, accy = 0.f;
    for (int j0 = s0; j0 < e0; j0 += 64) {
        int rem = e0 - j0;
        int m = rem < 64 ? rem : 64;
        int sv = 0; float wv = 0.f;
        if (lane < m) { int2 ec = csr2[j0 + lane]; sv = ec.x; wv = __int_as_float(ec.y); }
        int u = 0;
        for (; u + 4 <= m; u += 4) {
            int a0 = __shfl(sv, u + 0), a1 = __shfl(sv, u + 1);
            int a2 = __shfl(sv, u + 2), a3 = __shfl(sv, u + 3);
            float w0 = __shfl(wv, u + 0), w1 = __shfl(wv, u + 1);
            float w2 = __shfl(wv, u + 2), w3 = __shfl(wv, u + 3);
            float2 v0 = hW2[(size_t)a0 * 64 + lane];
            float2 v1 = hW2[(size_t)a1 * 64 + lane];
            float2 v2 = hW2[(size_t)a2 * 64 + lane];
            float2 v3 = hW2[(size_t)a3 * 64 + lane];
            accx += v0.x * w0 + v1.x * w1 + v2.x * w2 + v3.x * w3;
            accy += v0.y * w0 + v1.y * w1 + v2.y * w2 + v3.y * w3;
        }
        for (; u < m; ++u) {
            int s = __shfl(sv, u);
            float w = __shfl(wv, u);
            float2 v = hW2[(size_t)s * 64 + lane];
            accx += v.x * w; accy += v.y * w;
        }
    }
    float di = dis[i];
    float2 hv = hW2[(size_t)i * 64 + lane];
    float ox = fmaxf(di * accx + hv.x * (di * di) + bias[lane * 2], 0.f);
    float oy = fmaxf(di * accy + hv.y * (di * di) + bias[lane * 2 + 1], 0.f);
    float2 o; o.x = ox; o.y = oy;
    ((float2*)hout)[(size_t)i * 64 + lane] = o;
    float part = ox * Wsc[lane * 2] + oy * Wsc[lane * 2 + 1];
    #pragma unroll
    for (int sh = 32; sh >= 1; sh >>= 1) part += __shfl_xor(part, sh);
    if (lane == 0) { hs[i] = part; hsd[i] = part * di; }
}

// ---- fused: score gather (hsd via LDS) + top-k + newid + pool(tanh) + readout ----
template <int CAP, int K>
__global__ void score_topk_pool_k(const float* __restrict__ hout,
                                  const float* __restrict__ hs, const float* __restrict__ hsd,
                                  const int2* __restrict__ csr2, const int* __restrict__ off,
                                  const int* __restrict__ cnt, const float* __restrict__ dis,
                                  const float* __restrict__ bs,
                                  float* __restrict__ hA, float* __restrict__ z,
                                  int* __restrict__ newid, int cur) {
    __shared__ float v[CAP];
    __shared__ int ix[CAP];
    __shared__ float zm[CAP];
    __shared__ float zs[CAP];
    __shared__ float hl[CAP];
    int b = blockIdx.x, t = threadIdx.x;
    if (t < cur) hl[t] = hsd[b * cur + t];
    __syncthreads();
    // 1) score (GCN with shared CSR/dis), hsd gathered from LDS
    float sc = -INFINITY;
    if (t < cur) {
        int i = b * cur + t;
        int s0 = off[i], e0 = s0 + cnt[i];
        float acc = 0.f;
        int j = s0;
        for (; j + 4 <= e0; j += 4) {
            int x0 = csr2[j].x, x1 = csr2[j+1].x, x2 = csr2[j+2].x, x3 = csr2[j+3].x;
            acc += hl[x0 - b*cur] + hl[x1 - b*cur] + hl[x2 - b*cur] + hl[x3 - b*cur];
        }
        for (; j < e0; ++j) acc += hl[csr2[j].x - b*cur];
        float di = dis[i];
        sc = di * acc + hs[i] * (di * di) + bs[0];
    }
    v[t] = sc; ix[t] = t;
    __syncthreads();
    // 2) bitonic sort (value desc, idx asc)
    for (int size = 2; size <= CAP; size <<= 1) {
        for (int stride = size >> 1; stride > 0; stride >>= 1) {
            if (t < CAP / 2) {
                int pos = 2 * t - (t & (stride - 1));
                int j2 = pos + stride;
                bool asc = (pos & size) == 0;
                float v0 = v[pos], v1 = v[j2];
                int i0 = ix[pos], i1 = ix[j2];
                bool jb = (v1 > v0) || (v1 == v0 && i1 < i0);
                bool sw = asc ? jb : !jb;
                if (sw) { v[pos] = v1; v[j2] = v0; ix[pos] = i1; ix[j2] = i0; }
            }
            __syncthreads();
        }
    }
    // 3) newid for ALL of this graph's old nodes
    if (t < K)            newid[b * cur + ix[t]] = b * K + t;
    else if (ix[t] < cur) newid[b * cur + ix[t]] = -1;
    if (t < K) zm[t] = tanhf(v[t]);
    __syncthreads();
    // 4) pool gather + readout
    if constexpr (CAP >= 128) {
        const int G = CAP / 128;
        int g = t >> 7, f = t & 127;
        float vmax = -INFINITY, vsum = 0.f;
        for (int j = g; j < K; j += G) {
            int src = b * cur + ix[j];
            float val = hout[(size_t)src * 128 + f] * zm[j];
            hA[((size_t)b * K + j) * 128 + f] = val;
            vmax = fmaxf(vmax, val); vsum += val;
        }
        __syncthreads();
        zm[t] = vmax; zs[t] = vsum;
        __syncthreads();
        if (t < 128) {
            float m = zm[t], s2 = zs[t];
            for (int g2 = 1; g2 < G; ++g2) { m = fmaxf(m, zm[g2 * 128 + t]); s2 += zs[g2 * 128 + t]; }
            z[b * 256 + t] += m;
            z[b * 256 + 128 + t] += s2 / (float)K;
        }
    } else {
        float vmax0 = -INFINITY, vsum0 = 0.f, vmax1 = -INFINITY, vsum1 = 0.f;
        for (int j = 0; j < K; ++j) {
            int src = b * cur + ix[j];
            float gt = zm[j];
            float a = hout[(size_t)src * 128 + t] * gt;
            float c = hout[(size_t)src * 128 + 64 + t] * gt;
            hA[((size_t)b * K + j) * 128 + t] = a;
            hA[((size_t)b * K + j) * 128 + 64 + t] = c;
            vmax0 = fmaxf(vmax0, a); vsum0 += a;
            vmax1 = fmaxf(vmax1, c); vsum1 += c;
        }
        z[b * 256 + t] += vmax0;
        z[b * 256 + 64 + t] += vmax1;
        z[b * 256 + 128 + t] += vsum0 / (float)K;
        z[b * 256 + 192 + t] += vsum1 / (float)K;
    }
}

// ---------------- MLP head + log_softmax ----------------
__global__ void mlp_head_k(const float* __restrict__ z,
                           const float* __restrict__ Wl1, const float* __restrict__ bl1,
                           const float* __restrict__ Wl2, const float* __restrict__ bl2,
                           const float* __restrict__ Wl3, const float* __restrict__ bl3,
                           float* __restrict__ out) {
    __shared__ float zr[256], h1[128], h2[64], lg[NCLS], red[2];
    int b = blockIdx.x, t = threadIdx.x;  // 128 threads
    zr[t] = z[b * 256 + t];
    zr[t + 128] = z[b * 256 + 128 + t];
    __syncthreads();
    float acc = bl1[t];
    #pragma unroll 8
    for (int i = 0; i < 256; ++i) acc += zr[i] * Wl1[i * 128 + t];
    h1[t] = fmaxf(acc, 0.f);
    __syncthreads();
    if (t < 64) {
        float a2 = bl2[t];
        #pragma unroll 8
        for (int i = 0; i < 128; ++i) a2 += h1[i] * Wl2[i * 64 + t];
        h2[t] = fmaxf(a2, 0.f);
    }
    __syncthreads();
    if (t < NCLS) {
        float a3 = bl3[t];
        #pragma unroll 8
        for (int i = 0; i < 64; ++i) a3 += h2[i] * Wl3[i * NCLS + t];
        lg[t] = a3;
    }
    __syncthreads();
    if (t == 0) {
        float m = lg[0];
        for (int i = 1; i < NCLS; ++i) m = fmaxf(m, lg[i]);
        float s = 0.f;
        for (int i = 0; i < NCLS; ++i) s += expf(lg[i] - m);
        red[0] = m; red[1] = logf(s);
    }
    __syncthreads();
    if (t < NCLS) out[b * NCLS + t] = lg[t] - red[0] - red[1];
}

// ---------------- host ----------------
extern "C" void kernel_launch(void* const* d_in, const int* in_sizes, int n_in,
                              void* d_out, int out_size, void* d_ws, size_t ws_size,
                              hipStream_t stream) {
    const float* x   = (const float*)d_in[0];
    const int*   ei  = (const int*)d_in[1];
    const float* W1  = (const float*)d_in[2];  const float* b1  = (const float*)d_in[3];
    const float* W2  = (const float*)d_in[4];  const float* b2  = (const float*)d_in[5];
    const float* W3  = (const float*)d_in[6];  const float* b3  = (const float*)d_in[7];
    const float* Ws1 = (const float*)d_in[8];  const float* bs1 = (const float*)d_in[9];
    const float* Ws2 = (const float*)d_in[10]; const float* bs2 = (const float*)d_in[11];
    const float* Ws3 = (const float*)d_in[12]; const float* bs3 = (const float*)d_in[13];
    const float* Wl1 = (const float*)d_in[14]; const float* bl1 = (const float*)d_in[15];
    const float* Wl2 = (const float*)d_in[16]; const float* bl2 = (const float*)d_in[17];
    const float* Wl3 = (const float*)d_in[18]; const float* bl3 = (const float*)d_in[19];
    float* out = (float*)d_out;

    const int NMAX = NB * N0;  // 65536
    const int N1 = NB * KP1;   // 13120
    const int N2 = NB * KP2;   // 2624

    char* p = (char*)d_ws;
    // --- zeroed-once region: cnt0, cnt1, cnt2, gctr, z ---
    int*   cnt0 = (int*)p;   p += (size_t)NMAX * 4;
    int*   cnt1 = (int*)p;   p += (size_t)N1 * 4;
    int*   cnt2 = (int*)p;   p += (size_t)N2 * 4;
    int*   gctr = (int*)p;   p += 8 * 4;   // [0..2]=CSR bases, [3]=ec2, [4]=ec3
    float* z    = (float*)p; p += (size_t)NB * 256 * 4;
    size_t zero_bytes = (size_t)(p - (char*)d_ws);
    // --- rest ---
    float* hW     = (float*)p; p += (size_t)N1 * 128 * 4;     // stage2/3 gemm out
    float* hout   = (float*)p; p += (size_t)NMAX * 128 * 4;
    float* hA     = (float*)p; p += (size_t)N1 * 128 * 4;
    float* y      = (float*)p; p += (size_t)NMAX * FIN * 4;
    float* dis    = (float*)p; p += (size_t)NMAX * 4;
    float* hs     = (float*)p; p += (size_t)NMAX * 4;
    float* hsd    = (float*)p; p += (size_t)NMAX * 4;
    int* newid    = (int*)p;   p += (size_t)NMAX * 4;
    int* off      = (int*)p;   p += (size_t)NMAX * 4;
    int* cursor   = (int*)p;   p += (size_t)NMAX * 4;
    int2* ebuf    = (int2*)p;  p += (size_t)NEDGE * 8;
    int2* ebuf2   = (int2*)p;  p += (size_t)NEDGE * 8;
    int2* csr2    = (int2*)p;  p += (size_t)NEDGE * 8;

    const int EB = ceil_div(NEDGE, 256);

    hipMemsetAsync(d_ws, 0, zero_bytes, stream);
    init_edges_count_k<<<EB, 256, 0, stream>>>(ei, ebuf, cnt0);

    // ---------------- stage 1 ----------------
    offsets_k<<<NMAX / 256, 256, 0, stream>>>(cnt0, off, cursor, dis, gctr + 0, NMAX);
    scatter1_k<<<EB, 256, 0, stream>>>(ebuf, cursor, dis, csr2);
    agg10_k<<<NB * 4, 256, 0, stream>>>(x, csr2, off, cnt0, dis, y);
    gemm_fin_fused_k<<<NMAX / 4, 256, 0, stream>>>(y, W1, b1, Ws1, dis, hout, hs, hsd, NMAX);
    score_topk_pool_k<1024, KP1><<<NB, 1024, 0, stream>>>(
        hout, hs, hsd, csr2, off, cnt0, dis, bs1, hA, z, newid, N0);
    edge_compact1_k<<<EB, 256, 0, stream>>>(ebuf, newid, ebuf2, cnt1, gctr + 3);

    // ---------------- stage 2 ----------------
    {
        dim3 g(ceil_div(N1, 64), 2);
        gemm128_tiled_k<<<g, 256, 0, stream>>>(hA, W2, hW, N1);
    }
    offsets_k<<<ceil_div(N1, 256), 256, 0, stream>>>(cnt1, off, cursor, dis, gctr + 1, N1);
    scatter_dyn_k<<<256, 256, 0, stream>>>(ebuf2, gctr + 3, cursor, dis, csr2);
    gcn_agg_fused2_k<<<N1 / 4, 256, 0, stream>>>(
        hW, csr2, off, cnt1, dis, b2, Ws2, hout, hs, hsd, N1, N1 / 32);
    score_topk_pool_k<256, KP2><<<NB, 256, 0, stream>>>(
        hout, hs, hsd, csr2, off, cnt1, dis, bs2, hA, z, newid, KP1);
    edge_compact_dyn_k<<<256, 256, 0, stream>>>(ebuf2, gctr + 3, newid, ebuf, cnt2, gctr + 4);

    // ---------------- stage 3 ----------------
    {
        dim3 g(ceil_div(N2, 64), 2);
        gemm128_tiled_k<<<g, 256, 0, stream>>>(hA, W3, hW, N2);
    }
    offsets_k<<<ceil_div(N2, 256), 256, 0, stream>>>(cnt2, off, cursor, dis, gctr + 2, N2);
    scatter_dyn_k<<<256, 256, 0, stream>>>(ebuf, gctr + 4, cursor, dis, csr2);
    gcn_agg_fused2_k<<<N2 / 4, 256, 0, stream>>>(
        hW, csr2, off, cnt2, dis, b3, Ws3, hout, hs, hsd, N2, N2 / 32);
    score_topk_pool_k<64, KP3><<<NB, 64, 0, stream>>>(
        hout, hs, hsd, csr2, off, cnt2, dis, bs3, hA, z, newid, KP2);

    mlp_head_k<<<NB, 128, 0, stream>>>(z, Wl1, bl1, Wl2, bl2, Wl3, bl3, out);
}

// Round 9
// 389.117 us; speedup vs baseline: 1.3571x; 1.3571x over previous
//
#include <hip/hip_runtime.h>
#include <math.h>

#define NB 64          // graphs
#define N0 1024        // nodes per graph (stage 1)
#define NEDGE 1048576  // total edges
#define FIN 10
#define NCLS 10
#define KP1 205
#define KP2 41
#define KP3 9

static inline int ceil_div(int a, int b) { return (a + b - 1) / b; }

// ---------------- edge init (int2, fused degree count) ----------------
__global__ void init_edges_count_k(const int* __restrict__ ei, int2* __restrict__ eb,
                                   int* __restrict__ cnt) {
    int e = blockIdx.x * blockDim.x + threadIdx.x;
    if (e >= NEDGE) return;
    int2 ed; ed.x = ei[e]; ed.y = ei[NEDGE + e];
    eb[e] = ed;
    atomicAdd(&cnt[ed.y], 1);
}

// ---------------- CSR offsets: per-block scan + atomic block base ----------------
// Region ORDER across nodes is arbitrary — only disjointness matters for the gather.
__global__ void offsets_k(const int* __restrict__ cnt, int* __restrict__ off,
                          int* __restrict__ cursor, float* __restrict__ dis,
                          int* __restrict__ gctr, int n) {
    __shared__ int buf[256];
    __shared__ int base;
    int i = blockIdx.x * 256 + threadIdx.x;
    int v = (i < n) ? cnt[i] : 0;
    buf[threadIdx.x] = v;
    __syncthreads();
    #pragma unroll
    for (int s = 1; s < 256; s <<= 1) {
        int t = (threadIdx.x >= s) ? buf[threadIdx.x - s] : 0;
        __syncthreads();
        buf[threadIdx.x] += t;
        __syncthreads();
    }
    if (threadIdx.x == 255) base = atomicAdd(gctr, buf[255]);
    __syncthreads();
    if (i < n) {
        int excl = base + buf[threadIdx.x] - v;
        off[i] = excl;
        cursor[i] = excl;
        dis[i] = rsqrtf((float)v + 1.0f);
    }
}

// ---------------- scatter: csr2 = {src, dis[src]} ----------------
__global__ void scatter1_k(const int2* __restrict__ eb, int* __restrict__ cursor,
                           const float* __restrict__ dis, int2* __restrict__ csr2) {
    int e = blockIdx.x * blockDim.x + threadIdx.x;
    if (e >= NEDGE) return;
    int2 ed = eb[e];
    int p = atomicAdd(&cursor[ed.y], 1);
    int2 o; o.x = ed.x; o.y = __float_as_int(dis[ed.x]);
    csr2[p] = o;
}

__global__ void scatter_dyn_k(const int2* __restrict__ eb, const int* __restrict__ nct,
                              int* __restrict__ cursor, const float* __restrict__ dis,
                              int2* __restrict__ csr2) {
    int total = *nct;
    for (int e = blockIdx.x * blockDim.x + threadIdx.x; e < total; e += gridDim.x * blockDim.x) {
        int2 ed = eb[e];
        int p = atomicAdd(&cursor[ed.y], 1);
        int2 o; o.x = ed.x; o.y = __float_as_int(dis[ed.x]);
        csr2[p] = o;
    }
}

// ------------- edge remap + COMPACT alive edges (block-scan, 1 atomic/block) ------
__global__ void edge_compact1_k(const int2* __restrict__ ebin, const int* __restrict__ newid,
                                int2* __restrict__ ebout, int* __restrict__ cntN,
                                int* __restrict__ ectr) {
    __shared__ int wsum[4];
    __shared__ int sbase;
    int e = blockIdx.x * 256 + threadIdx.x;
    int ns = -1, nd = -1;
    if (e < NEDGE) {
        int2 ed = ebin[e];
        ns = newid[ed.x]; nd = newid[ed.y];
    }
    bool alive = (ns >= 0 && nd >= 0);
    unsigned long long mask = __ballot(alive);
    int lane = threadIdx.x & 63, wid = threadIdx.x >> 6;
    int before = __popcll(mask & ((1ull << lane) - 1ull));
    if (lane == 0) wsum[wid] = __popcll(mask);
    __syncthreads();
    if (threadIdx.x == 0)
        sbase = atomicAdd(ectr, wsum[0] + wsum[1] + wsum[2] + wsum[3]);
    __syncthreads();
    if (alive) {
        int wbase = sbase;
        for (int w = 0; w < wid; ++w) wbase += wsum[w];
        atomicAdd(&cntN[nd], 1);
        int2 o; o.x = ns; o.y = nd;
        ebout[wbase + before] = o;
    }
}

__global__ void edge_compact_dyn_k(const int2* __restrict__ ebin, const int* __restrict__ nct,
                                   const int* __restrict__ newid, int2* __restrict__ ebout,
                                   int* __restrict__ cntN, int* __restrict__ ectr) {
    __shared__ int wsum[4];
    __shared__ int sbase;
    int total = *nct;
    int stride = gridDim.x * blockDim.x;
    int iters = (total + stride - 1) / stride;
    for (int it = 0; it < iters; ++it) {
        int e = it * stride + blockIdx.x * 256 + threadIdx.x;
        int ns = -1, nd = -1;
        if (e < total) {
            int2 ed = ebin[e];
            ns = newid[ed.x]; nd = newid[ed.y];
        }
        bool alive = (ns >= 0 && nd >= 0);
        unsigned long long mask = __ballot(alive);
        int lane = threadIdx.x & 63, wid = threadIdx.x >> 6;
        int before = __popcll(mask & ((1ull << lane) - 1ull));
        if (lane == 0) wsum[wid] = __popcll(mask);
        __syncthreads();
        if (threadIdx.x == 0)
            sbase = atomicAdd(ectr, wsum[0] + wsum[1] + wsum[2] + wsum[3]);
        __syncthreads();
        if (alive) {
            int wbase = sbase;
            for (int w = 0; w < wid; ++w) wbase += wsum[w];
            atomicAdd(&cntN[nd], 1);
            int2 o; o.x = ns; o.y = nd;
            ebout[wbase + before] = o;
        }
        __syncthreads();
    }
}

// ---------------- stage-1: aggregate RAW x (10-dim) pre-GEMM, LDS-staged graph ----
// y_i = dis_i * sum_j x[s_j]*dis_sj + dis_i^2 * x_i     (10 floats per node)
__global__ __launch_bounds__(256) void agg10_k(const float* __restrict__ x,
                                               const int2* __restrict__ csr2,
                                               const int* __restrict__ off,
                                               const int* __restrict__ cnt,
                                               const float* __restrict__ dis,
                                               float* __restrict__ y) {
    __shared__ float xl[N0 * 11];  // rows padded to 11 floats (bank spread)
    int b = blockIdx.x >> 2, chunk = blockIdx.x & 3;
    const float* xg = x + (size_t)b * (N0 * FIN);
    for (int u = threadIdx.x; u < N0 * FIN; u += 256) {
        int r = u / FIN, c = u - r * FIN;
        xl[r * 11 + c] = xg[u];
    }
    __syncthreads();
    int li = chunk * 256 + threadIdx.x;
    int i  = b * N0 + li;
    int s0 = off[i], m = cnt[i];
    int base = b * N0;
    float acc[FIN];
    #pragma unroll
    for (int f = 0; f < FIN; ++f) acc[f] = 0.f;
    int j = 0;
    for (; j + 2 <= m; j += 2) {
        int2 e0 = csr2[s0 + j], e1 = csr2[s0 + j + 1];
        int sl0 = (e0.x - base) * 11, sl1 = (e1.x - base) * 11;
        float w0 = __int_as_float(e0.y), w1 = __int_as_float(e1.y);
        #pragma unroll
        for (int f = 0; f < FIN; ++f) acc[f] += xl[sl0 + f] * w0 + xl[sl1 + f] * w1;
    }
    if (j < m) {
        int2 e0 = csr2[s0 + j];
        int sl0 = (e0.x - base) * 11;
        float w0 = __int_as_float(e0.y);
        #pragma unroll
        for (int f = 0; f < FIN; ++f) acc[f] += xl[sl0 + f] * w0;
    }
    float di = dis[i], d2 = di * di;
    #pragma unroll
    for (int f = 0; f < FIN; ++f)
        y[(size_t)i * FIN + f] = di * acc[f] + d2 * xl[li * 11 + f];
}

// ---------------- fused: hout = relu(y@W + b); hs = hout@Wsc; hsd = hs*dis -------
__global__ void gemm_fin_fused_k(const float* __restrict__ y, const float* __restrict__ W,
                                 const float* __restrict__ bb, const float* __restrict__ Wsc,
                                 const float* __restrict__ dis,
                                 float* __restrict__ hout, float* __restrict__ hs,
                                 float* __restrict__ hsd, int n) {
    __shared__ float Ws[FIN * 128];
    __shared__ float Sc[128];
    for (int u = threadIdx.x; u < FIN * 128; u += 256) Ws[u] = W[u];
    if (threadIdx.x < 128) Sc[threadIdx.x] = Wsc[threadIdx.x];
    __syncthreads();
    int t = blockIdx.x * 256 + threadIdx.x;
    int i = t >> 6, lane = threadIdx.x & 63;
    if (i >= n) return;
    float a = (lane < FIN) ? y[(size_t)i * FIN + lane] : 0.f;
    const float2* W2 = (const float2*)Ws;
    float ax = bb[lane * 2], ay = bb[lane * 2 + 1];
    #pragma unroll
    for (int k = 0; k < FIN; ++k) {
        float ak = __shfl(a, k);
        float2 w = W2[k * 64 + lane];
        ax += ak * w.x; ay += ak * w.y;
    }
    ax = fmaxf(ax, 0.f); ay = fmaxf(ay, 0.f);
    float2 o; o.x = ax; o.y = ay;
    ((float2*)hout)[(size_t)i * 64 + lane] = o;
    float part = ax * Sc[lane * 2] + ay * Sc[lane * 2 + 1];
    #pragma unroll
    for (int sh = 32; sh >= 1; sh >>= 1) part += __shfl_xor(part, sh);
    if (lane == 0) { hs[i] = part; hsd[i] = part * dis[i]; }
}

// ---------------- GEMM (K=128): 64x64 tile, 4x4 per thread, register-tiled -----
__global__ __launch_bounds__(256) void gemm128_tiled_k(const float* __restrict__ A,
                                                       const float* __restrict__ W,
                                                       float* __restrict__ C, int n) {
    __shared__ float As[64][33];
    __shared__ float Wt[32][64];
    int tx = threadIdx.x & 15, ty = threadIdx.x >> 4;
    int r0 = blockIdx.x * 64;
    int c0 = blockIdx.y * 64;
    float4 acc0 = {0,0,0,0}, acc1 = {0,0,0,0}, acc2 = {0,0,0,0}, acc3 = {0,0,0,0};
    int u = threadIdx.x;
    for (int k0 = 0; k0 < 128; k0 += 32) {
        __syncthreads();
        {
            int rr = u >> 3, cc = (u & 7) * 4;
            #pragma unroll
            for (int h = 0; h < 2; ++h) {
                int r = rr + h * 32;
                float4 v = {0,0,0,0};
                if (r0 + r < n) v = *(const float4*)&A[(size_t)(r0 + r) * 128 + k0 + cc];
                As[r][cc] = v.x; As[r][cc+1] = v.y; As[r][cc+2] = v.z; As[r][cc+3] = v.w;
            }
        }
        {
            int kk = u >> 4, c = (u & 15) * 4;
            #pragma unroll
            for (int h = 0; h < 2; ++h) {
                float4 v = *(const float4*)&W[(size_t)(k0 + kk + h * 16) * 128 + c0 + c];
                *(float4*)&Wt[kk + h * 16][c] = v;
            }
        }
        __syncthreads();
        #pragma unroll
        for (int kk = 0; kk < 32; ++kk) {
            float4 wv = *(const float4*)&Wt[kk][tx * 4];
            float a0 = As[ty * 4 + 0][kk];
            float a1 = As[ty * 4 + 1][kk];
            float a2 = As[ty * 4 + 2][kk];
            float a3 = As[ty * 4 + 3][kk];
            acc0.x += a0 * wv.x; acc0.y += a0 * wv.y; acc0.z += a0 * wv.z; acc0.w += a0 * wv.w;
            acc1.x += a1 * wv.x; acc1.y += a1 * wv.y; acc1.z += a1 * wv.z; acc1.w += a1 * wv.w;
            acc2.x += a2 * wv.x; acc2.y += a2 * wv.y; acc2.z += a2 * wv.z; acc2.w += a2 * wv.w;
            acc3.x += a3 * wv.x; acc3.y += a3 * wv.y; acc3.z += a3 * wv.z; acc3.w += a3 * wv.w;
        }
    }
    int r = r0 + ty * 4;
    if (r + 0 < n) *(float4*)&C[(size_t)(r + 0) * 128 + c0 + tx * 4] = acc0;
    if (r + 1 < n) *(float4*)&C[(size_t)(r + 1) * 128 + c0 + tx * 4] = acc1;
    if (r + 2 < n) *(float4*)&C[(size_t)(r + 2) * 128 + c0 + tx * 4] = acc2;
    if (r + 3 < n) *(float4*)&C[(size_t)(r + 3) * 128 + c0 + tx * 4] = acc3;
}

// ---------- fused GCN aggregation (stages 2/3): wave-per-node, csr2, XCD-swizzled --
__global__ void gcn_agg_fused2_k(const float* __restrict__ hW, const int2* __restrict__ csr2,
                                 const int* __restrict__ off, const int* __restrict__ cnt,
                                 const float* __restrict__ dis, const float* __restrict__ bias,
                                 const float* __restrict__ Wsc,
                                 float* __restrict__ hout, float* __restrict__ hs,
                                 float* __restrict__ hsd, int n, int cpx) {
    int wg = ((blockIdx.x & 7) * cpx) + (blockIdx.x >> 3);
    int t = wg * blockDim.x + threadIdx.x;
    int i = t >> 6;              // one wave per node
    int lane = threadIdx.x & 63;
    if (i >= n) return;
    const float2* hW2 = (const float2*)hW;
    int s0 = off[i], e0 = s0 + cnt[i];
    float accx = 0.f, accy = 0.f;
    for (int j0 = s0; j0 < e0; j0 += 64) {
        int rem = e0 - j0;
        int m = rem < 64 ? rem : 64;
        int sv = 0; float wv = 0.f;
        if (lane < m) { int2 ec = csr2[j0 + lane]; sv = ec.x; wv = __int_as_float(ec.y); }
        int u = 0;
        for (; u + 4 <= m; u += 4) {
            int a0 = __shfl(sv, u + 0), a1 = __shfl(sv, u + 1);
            int a2 = __shfl(sv, u + 2), a3 = __shfl(sv, u + 3);
            float w0 = __shfl(wv, u + 0), w1 = __shfl(wv, u + 1);
            float w2 = __shfl(wv, u + 2), w3 = __shfl(wv, u + 3);
            float2 v0 = hW2[(size_t)a0 * 64 + lane];
            float2 v1 = hW2[(size_t)a1 * 64 + lane];
            float2 v2 = hW2[(size_t)a2 * 64 + lane];
            float2 v3 = hW2[(size_t)a3 * 64 + lane];
            accx += v0.x * w0 + v1.x * w1 + v2.x * w2 + v3.x * w3;
            accy += v0.y * w0 + v1.y * w1 + v2.y * w2 + v3.y * w3;
        }
        for (; u < m; ++u) {
            int s = __shfl(sv, u);
            float w = __shfl(wv, u);
            float2 v = hW2[(size_t)s * 64 + lane];
            accx += v.x * w; accy += v.y * w;
        }
    }
    float di = dis[i];
    float2 hv = hW2[(size_t)i * 64 + lane];
    float ox = fmaxf(di * accx + hv.x * (di * di) + bias[lane * 2], 0.f);
    float oy = fmaxf(di * accy + hv.y * (di * di) + bias[lane * 2 + 1], 0.f);
    float2 o; o.x = ox; o.y = oy;
    ((float2*)hout)[(size_t)i * 64 + lane] = o;
    float part = ox * Wsc[lane * 2] + oy * Wsc[lane * 2 + 1];
    #pragma unroll
    for (int sh = 32; sh >= 1; sh >>= 1) part += __shfl_xor(part, sh);
    if (lane == 0) { hs[i] = part; hsd[i] = part * di; }
}

// ---- fused: score gather (hsd via LDS) + top-k + newid + pool(tanh) + readout ----
template <int CAP, int K>
__global__ void score_topk_pool_k(const float* __restrict__ hout,
                                  const float* __restrict__ hs, const float* __restrict__ hsd,
                                  const int2* __restrict__ csr2, const int* __restrict__ off,
                                  const int* __restrict__ cnt, const float* __restrict__ dis,
                                  const float* __restrict__ bs,
                                  float* __restrict__ hA, float* __restrict__ z,
                                  int* __restrict__ newid, int cur) {
    __shared__ float v[CAP];
    __shared__ int ix[CAP];
    __shared__ float zm[CAP];
    __shared__ float zs[CAP];
    __shared__ float hl[CAP];
    int b = blockIdx.x, t = threadIdx.x;
    if (t < cur) hl[t] = hsd[b * cur + t];
    __syncthreads();
    // 1) score (GCN with shared CSR/dis), hsd gathered from LDS
    float sc = -INFINITY;
    if (t < cur) {
        int i = b * cur + t;
        int s0 = off[i], e0 = s0 + cnt[i];
        float acc = 0.f;
        int j = s0;
        for (; j + 4 <= e0; j += 4) {
            int x0 = csr2[j].x, x1 = csr2[j+1].x, x2 = csr2[j+2].x, x3 = csr2[j+3].x;
            acc += hl[x0 - b*cur] + hl[x1 - b*cur] + hl[x2 - b*cur] + hl[x3 - b*cur];
        }
        for (; j < e0; ++j) acc += hl[csr2[j].x - b*cur];
        float di = dis[i];
        sc = di * acc + hs[i] * (di * di) + bs[0];
    }
    v[t] = sc; ix[t] = t;
    __syncthreads();
    // 2) bitonic sort (value desc, idx asc)
    for (int size = 2; size <= CAP; size <<= 1) {
        for (int stride = size >> 1; stride > 0; stride >>= 1) {
            if (t < CAP / 2) {
                int pos = 2 * t - (t & (stride - 1));
                int j2 = pos + stride;
                bool asc = (pos & size) == 0;
                float v0 = v[pos], v1 = v[j2];
                int i0 = ix[pos], i1 = ix[j2];
                bool jb = (v1 > v0) || (v1 == v0 && i1 < i0);
                bool sw = asc ? jb : !jb;
                if (sw) { v[pos] = v1; v[j2] = v0; ix[pos] = i1; ix[j2] = i0; }
            }
            __syncthreads();
        }
    }
    // 3) newid for ALL of this graph's old nodes
    if (t < K)            newid[b * cur + ix[t]] = b * K + t;
    else if (ix[t] < cur) newid[b * cur + ix[t]] = -1;
    if (t < K) zm[t] = tanhf(v[t]);
    __syncthreads();
    // 4) pool gather + readout
    if constexpr (CAP >= 128) {
        const int G = CAP / 128;
        int g = t >> 7, f = t & 127;
        float vmax = -INFINITY, vsum = 0.f;
        for (int j = g; j < K; j += G) {
            int src = b * cur + ix[j];
            float val = hout[(size_t)src * 128 + f] * zm[j];
            hA[((size_t)b * K + j) * 128 + f] = val;
            vmax = fmaxf(vmax, val); vsum += val;
        }
        __syncthreads();
        zm[t] = vmax; zs[t] = vsum;
        __syncthreads();
        if (t < 128) {
            float m = zm[t], s2 = zs[t];
            for (int g2 = 1; g2 < G; ++g2) { m = fmaxf(m, zm[g2 * 128 + t]); s2 += zs[g2 * 128 + t]; }
            z[b * 256 + t] += m;
            z[b * 256 + 128 + t] += s2 / (float)K;
        }
    } else {
        float vmax0 = -INFINITY, vsum0 = 0.f, vmax1 = -INFINITY, vsum1 = 0.f;
        for (int j = 0; j < K; ++j) {
            int src = b * cur + ix[j];
            float gt = zm[j];
            float a = hout[(size_t)src * 128 + t] * gt;
            float c = hout[(size_t)src * 128 + 64 + t] * gt;
            hA[((size_t)b * K + j) * 128 + t] = a;
            hA[((size_t)b * K + j) * 128 + 64 + t] = c;
            vmax0 = fmaxf(vmax0, a); vsum0 += a;
            vmax1 = fmaxf(vmax1, c); vsum1 += c;
        }
        z[b * 256 + t] += vmax0;
        z[b * 256 + 64 + t] += vmax1;
        z[b * 256 + 128 + t] += vsum0 / (float)K;
        z[b * 256 + 192 + t] += vsum1 / (float)K;
    }
}

// ---------------- MLP head + log_softmax ----------------
__global__ void mlp_head_k(const float* __restrict__ z,
                           const float* __restrict__ Wl1, const float* __restrict__ bl1,
                           const float* __restrict__ Wl2, const float* __restrict__ bl2,
                           const float* __restrict__ Wl3, const float* __restrict__ bl3,
                           float* __restrict__ out) {
    __shared__ float zr[256], h1[128], h2[64], lg[NCLS], red[2];
    int b = blockIdx.x, t = threadIdx.x;  // 128 threads
    zr[t] = z[b * 256 + t];
    zr[t + 128] = z[b * 256 + 128 + t];
    __syncthreads();
    float acc = bl1[t];
    #pragma unroll 8
    for (int i = 0; i < 256; ++i) acc += zr[i] * Wl1[i * 128 + t];
    h1[t] = fmaxf(acc, 0.f);
    __syncthreads();
    if (t < 64) {
        float a2 = bl2[t];
        #pragma unroll 8
        for (int i = 0; i < 128; ++i) a2 += h1[i] * Wl2[i * 64 + t];
        h2[t] = fmaxf(a2, 0.f);
    }
    __syncthreads();
    if (t < NCLS) {
        float a3 = bl3[t];
        #pragma unroll 8
        for (int i = 0; i < 64; ++i) a3 += h2[i] * Wl3[i * NCLS + t];
        lg[t] = a3;
    }
    __syncthreads();
    if (t == 0) {
        float m = lg[0];
        for (int i = 1; i < NCLS; ++i) m = fmaxf(m, lg[i]);
        float s = 0.f;
        for (int i = 0; i < NCLS; ++i) s += expf(lg[i] - m);
        red[0] = m; red[1] = logf(s);
    }
    __syncthreads();
    if (t < NCLS) out[b * NCLS + t] = lg[t] - red[0] - red[1];
}

// ---------------- host ----------------
extern "C" void kernel_launch(void* const* d_in, const int* in_sizes, int n_in,
                              void* d_out, int out_size, void* d_ws, size_t ws_size,
                              hipStream_t stream) {
    const float* x   = (const float*)d_in[0];
    const int*   ei  = (const int*)d_in[1];
    const float* W1  = (const float*)d_in[2];  const float* b1  = (const float*)d_in[3];
    const float* W2  = (const float*)d_in[4];  const float* b2  = (const float*)d_in[5];
    const float* W3  = (const float*)d_in[6];  const float* b3  = (const float*)d_in[7];
    const float* Ws1 = (const float*)d_in[8];  const float* bs1 = (const float*)d_in[9];
    const float* Ws2 = (const float*)d_in[10]; const float* bs2 = (const float*)d_in[11];
    const float* Ws3 = (const float*)d_in[12]; const float* bs3 = (const float*)d_in[13];
    const float* Wl1 = (const float*)d_in[14]; const float* bl1 = (const float*)d_in[15];
    const float* Wl2 = (const float*)d_in[16]; const float* bl2 = (const float*)d_in[17];
    const float* Wl3 = (const float*)d_in[18]; const float* bl3 = (const float*)d_in[19];
    float* out = (float*)d_out;

    const int NMAX = NB * N0;  // 65536
    const int N1 = NB * KP1;   // 13120
    const int N2 = NB * KP2;   // 2624

    char* p = (char*)d_ws;
    // --- zeroed-once region: cnt0, cnt1, cnt2, gctr, z ---
    int*   cnt0 = (int*)p;   p += (size_t)NMAX * 4;
    int*   cnt1 = (int*)p;   p += (size_t)N1 * 4;
    int*   cnt2 = (int*)p;   p += (size_t)N2 * 4;
    int*   gctr = (int*)p;   p += 8 * 4;   // [0..2]=CSR bases, [3]=ec2, [4]=ec3
    float* z    = (float*)p; p += (size_t)NB * 256 * 4;
    size_t zero_bytes = (size_t)(p - (char*)d_ws);
    // --- rest ---
    float* hW     = (float*)p; p += (size_t)N1 * 128 * 4;     // stage2/3 gemm out
    float* hout   = (float*)p; p += (size_t)NMAX * 128 * 4;
    float* hA     = (float*)p; p += (size_t)N1 * 128 * 4;
    float* y      = (float*)p; p += (size_t)NMAX * FIN * 4;
    float* dis    = (float*)p; p += (size_t)NMAX * 4;
    float* hs     = (float*)p; p += (size_t)NMAX * 4;
    float* hsd    = (float*)p; p += (size_t)NMAX * 4;
    int* newid    = (int*)p;   p += (size_t)NMAX * 4;
    int* off      = (int*)p;   p += (size_t)NMAX * 4;
    int* cursor   = (int*)p;   p += (size_t)NMAX * 4;
    int2* ebuf    = (int2*)p;  p += (size_t)NEDGE * 8;
    int2* ebuf2   = (int2*)p;  p += (size_t)NEDGE * 8;
    int2* csr2    = (int2*)p;  p += (size_t)NEDGE * 8;

    const int EB = ceil_div(NEDGE, 256);

    hipMemsetAsync(d_ws, 0, zero_bytes, stream);
    init_edges_count_k<<<EB, 256, 0, stream>>>(ei, ebuf, cnt0);

    // ---------------- stage 1 ----------------
    offsets_k<<<NMAX / 256, 256, 0, stream>>>(cnt0, off, cursor, dis, gctr + 0, NMAX);
    scatter1_k<<<EB, 256, 0, stream>>>(ebuf, cursor, dis, csr2);
    agg10_k<<<NB * 4, 256, 0, stream>>>(x, csr2, off, cnt0, dis, y);
    gemm_fin_fused_k<<<NMAX / 4, 256, 0, stream>>>(y, W1, b1, Ws1, dis, hout, hs, hsd, NMAX);
    score_topk_pool_k<1024, KP1><<<NB, 1024, 0, stream>>>(
        hout, hs, hsd, csr2, off, cnt0, dis, bs1, hA, z, newid, N0);
    edge_compact1_k<<<EB, 256, 0, stream>>>(ebuf, newid, ebuf2, cnt1, gctr + 3);

    // ---------------- stage 2 ----------------
    {
        dim3 g(ceil_div(N1, 64), 2);
        gemm128_tiled_k<<<g, 256, 0, stream>>>(hA, W2, hW, N1);
    }
    offsets_k<<<ceil_div(N1, 256), 256, 0, stream>>>(cnt1, off, cursor, dis, gctr + 1, N1);
    scatter_dyn_k<<<256, 256, 0, stream>>>(ebuf2, gctr + 3, cursor, dis, csr2);
    gcn_agg_fused2_k<<<N1 / 4, 256, 0, stream>>>(
        hW, csr2, off, cnt1, dis, b2, Ws2, hout, hs, hsd, N1, N1 / 32);
    score_topk_pool_k<256, KP2><<<NB, 256, 0, stream>>>(
        hout, hs, hsd, csr2, off, cnt1, dis, bs2, hA, z, newid, KP1);
    edge_compact_dyn_k<<<256, 256, 0, stream>>>(ebuf2, gctr + 3, newid, ebuf, cnt2, gctr + 4);

    // ---------------- stage 3 ----------------
    {
        dim3 g(ceil_div(N2, 64), 2);
        gemm128_tiled_k<<<g, 256, 0, stream>>>(hA, W3, hW, N2);
    }
    offsets_k<<<ceil_div(N2, 256), 256, 0, stream>>>(cnt2, off, cursor, dis, gctr + 2, N2);
    scatter_dyn_k<<<256, 256, 0, stream>>>(ebuf, gctr + 4, cursor, dis, csr2);
    gcn_agg_fused2_k<<<N2 / 4, 256, 0, stream>>>(
        hW, csr2, off, cnt2, dis, b3, Ws3, hout, hs, hsd, N2, N2 / 32);
    score_topk_pool_k<64, KP3><<<NB, 64, 0, stream>>>(
        hout, hs, hsd, csr2, off, cnt2, dis, bs3, hA, z, newid, KP2);

    mlp_head_k<<<NB, 128, 0, stream>>>(z, Wl1, bl1, Wl2, bl2, Wl3, bl3, out);
}

// Round 11
// 345.910 us; speedup vs baseline: 1.5266x; 1.1249x over previous
//
#include <hip/hip_runtime.h>
#include <math.h>

#define NB 64          // graphs
#define N0 1024        // nodes per graph (stage 1)
#define NEDGE 1048576  // total edges
#define FIN 10
#define NCLS 10
#define KP1 205
#define KP2 41
#define KP3 9

static inline int ceil_div(int a, int b) { return (a + b - 1) / b; }

// ---------------- stage-1 degree count straight from ei ----------------
__global__ void count1_k(const int* __restrict__ ei, int* __restrict__ cnt) {
    int e = blockIdx.x * blockDim.x + threadIdx.x;
    if (e >= NEDGE) return;
    atomicAdd(&cnt[ei[NEDGE + e]], 1);
}

// ---------------- CSR offsets: per-block scan + atomic block base ----------------
// Region ORDER across nodes is arbitrary — only disjointness matters for the gather.
__global__ void offsets_k(const int* __restrict__ cnt, int* __restrict__ off,
                          int* __restrict__ cursor, float* __restrict__ dis,
                          int* __restrict__ gctr, int n) {
    __shared__ int buf[256];
    __shared__ int base;
    int i = blockIdx.x * 256 + threadIdx.x;
    int v = (i < n) ? cnt[i] : 0;
    buf[threadIdx.x] = v;
    __syncthreads();
    #pragma unroll
    for (int s = 1; s < 256; s <<= 1) {
        int t = (threadIdx.x >= s) ? buf[threadIdx.x - s] : 0;
        __syncthreads();
        buf[threadIdx.x] += t;
        __syncthreads();
    }
    if (threadIdx.x == 255) base = atomicAdd(gctr, buf[255]);
    __syncthreads();
    if (i < n) {
        int excl = base + buf[threadIdx.x] - v;
        off[i] = excl;
        cursor[i] = excl;
        dis[i] = rsqrtf((float)v + 1.0f);
    }
}

// ---------------- stage-1 scatter straight from ei: csr2 = {src, dis[src]} -------
__global__ void scatter1_k(const int* __restrict__ ei, int* __restrict__ cursor,
                           const float* __restrict__ dis, int2* __restrict__ csr2) {
    int e = blockIdx.x * blockDim.x + threadIdx.x;
    if (e >= NEDGE) return;
    int s = ei[e], d = ei[NEDGE + e];
    int p = atomicAdd(&cursor[d], 1);
    int2 o; o.x = s; o.y = __float_as_int(dis[s]);
    csr2[p] = o;
}

// ---------------- generic scatter over int2 edge buffer (dead y=-1 skipped) ------
__global__ void scatter_k(const int2* __restrict__ eb, int* __restrict__ cursor,
                          const float* __restrict__ dis, int2* __restrict__ csr2) {
    int e = blockIdx.x * blockDim.x + threadIdx.x;
    if (e >= NEDGE) return;
    int2 ed = eb[e];
    if (ed.y < 0) return;
    int p = atomicAdd(&cursor[ed.y], 1);
    int2 o; o.x = ed.x; o.y = __float_as_int(dis[ed.x]);
    csr2[p] = o;
}

// -------- stage1->2: remap ORIGINAL edges via newid, write eb, count new deg -----
__global__ void edge_update1_k(const int* __restrict__ ei, const int* __restrict__ newid,
                               int2* __restrict__ eb, int* __restrict__ cntN) {
    int e = blockIdx.x * blockDim.x + threadIdx.x;
    if (e >= NEDGE) return;
    int ns = newid[ei[e]], nd = newid[ei[NEDGE + e]];
    int2 o;
    if (ns < 0 || nd < 0) { o.x = 0; o.y = -1; }
    else { o.x = ns; o.y = nd; atomicAdd(&cntN[nd], 1); }
    eb[e] = o;
}

// -------- stage2->3: remap eb via newid, write eb2, count new deg ----------------
__global__ void edge_update2_k(const int2* __restrict__ ebin, const int* __restrict__ newid,
                               int2* __restrict__ ebout, int* __restrict__ cntN) {
    int e = blockIdx.x * blockDim.x + threadIdx.x;
    if (e >= NEDGE) return;
    int2 ed = ebin[e];
    int2 o; o.x = 0; o.y = -1;
    if (ed.y >= 0) {
        int ns = newid[ed.x], nd = newid[ed.y];
        if (ns >= 0 && nd >= 0) { o.x = ns; o.y = nd; atomicAdd(&cntN[nd], 1); }
    }
    ebout[e] = o;
}

// ---------------- stage-1: aggregate RAW x (10-dim) pre-GEMM, LDS-staged graph ----
// y_i = dis_i * sum_j x[s_j]*dis_sj + dis_i^2 * x_i     (10 floats per node)
__global__ __launch_bounds__(256) void agg10_k(const float* __restrict__ x,
                                               const int2* __restrict__ csr2,
                                               const int* __restrict__ off,
                                               const int* __restrict__ cnt,
                                               const float* __restrict__ dis,
                                               float* __restrict__ y) {
    __shared__ float xl[N0 * 11];  // rows padded to 11 floats (bank spread)
    int b = blockIdx.x >> 2, chunk = blockIdx.x & 3;
    const float* xg = x + (size_t)b * (N0 * FIN);
    for (int u = threadIdx.x; u < N0 * FIN; u += 256) {
        int r = u / FIN, c = u - r * FIN;
        xl[r * 11 + c] = xg[u];
    }
    __syncthreads();
    int li = chunk * 256 + threadIdx.x;
    int i  = b * N0 + li;
    int s0 = off[i], m = cnt[i];
    int base = b * N0;
    float acc[FIN];
    #pragma unroll
    for (int f = 0; f < FIN; ++f) acc[f] = 0.f;
    int j = 0;
    for (; j + 2 <= m; j += 2) {
        int2 e0 = csr2[s0 + j], e1 = csr2[s0 + j + 1];
        int sl0 = (e0.x - base) * 11, sl1 = (e1.x - base) * 11;
        float w0 = __int_as_float(e0.y), w1 = __int_as_float(e1.y);
        #pragma unroll
        for (int f = 0; f < FIN; ++f) acc[f] += xl[sl0 + f] * w0 + xl[sl1 + f] * w1;
    }
    if (j < m) {
        int2 e0 = csr2[s0 + j];
        int sl0 = (e0.x - base) * 11;
        float w0 = __int_as_float(e0.y);
        #pragma unroll
        for (int f = 0; f < FIN; ++f) acc[f] += xl[sl0 + f] * w0;
    }
    float di = dis[i], d2 = di * di;
    #pragma unroll
    for (int f = 0; f < FIN; ++f)
        y[(size_t)i * FIN + f] = di * acc[f] + d2 * xl[li * 11 + f];
}

// ---------------- fused: hout = relu(y@W + b); hs = hout@Wsc; hsd = hs*dis -------
__global__ void gemm_fin_fused_k(const float* __restrict__ y, const float* __restrict__ W,
                                 const float* __restrict__ bb, const float* __restrict__ Wsc,
                                 const float* __restrict__ dis,
                                 float* __restrict__ hout, float* __restrict__ hs,
                                 float* __restrict__ hsd, int n) {
    __shared__ float Ws[FIN * 128];
    __shared__ float Sc[128];
    for (int u = threadIdx.x; u < FIN * 128; u += 256) Ws[u] = W[u];
    if (threadIdx.x < 128) Sc[threadIdx.x] = Wsc[threadIdx.x];
    __syncthreads();
    int t = blockIdx.x * 256 + threadIdx.x;
    int i = t >> 6, lane = threadIdx.x & 63;
    if (i >= n) return;
    float a = (lane < FIN) ? y[(size_t)i * FIN + lane] : 0.f;
    const float2* W2 = (const float2*)Ws;
    float ax = bb[lane * 2], ay = bb[lane * 2 + 1];
    #pragma unroll
    for (int k = 0; k < FIN; ++k) {
        float ak = __shfl(a, k);
        float2 w = W2[k * 64 + lane];
        ax += ak * w.x; ay += ak * w.y;
    }
    ax = fmaxf(ax, 0.f); ay = fmaxf(ay, 0.f);
    float2 o; o.x = ax; o.y = ay;
    ((float2*)hout)[(size_t)i * 64 + lane] = o;
    float part = ax * Sc[lane * 2] + ay * Sc[lane * 2 + 1];
    #pragma unroll
    for (int sh = 32; sh >= 1; sh >>= 1) part += __shfl_xor(part, sh);
    if (lane == 0) { hs[i] = part; hsd[i] = part * dis[i]; }
}

// ---------------- GEMM (K=128): 64x64 tile, 4x4 per thread, register-tiled -----
__global__ __launch_bounds__(256) void gemm128_tiled_k(const float* __restrict__ A,
                                                       const float* __restrict__ W,
                                                       float* __restrict__ C, int n) {
    __shared__ float As[64][33];
    __shared__ float Wt[32][64];
    int tx = threadIdx.x & 15, ty = threadIdx.x >> 4;
    int r0 = blockIdx.x * 64;
    int c0 = blockIdx.y * 64;
    float4 acc0 = {0,0,0,0}, acc1 = {0,0,0,0}, acc2 = {0,0,0,0}, acc3 = {0,0,0,0};
    int u = threadIdx.x;
    for (int k0 = 0; k0 < 128; k0 += 32) {
        __syncthreads();
        {
            int rr = u >> 3, cc = (u & 7) * 4;
            #pragma unroll
            for (int h = 0; h < 2; ++h) {
                int r = rr + h * 32;
                float4 v = {0,0,0,0};
                if (r0 + r < n) v = *(const float4*)&A[(size_t)(r0 + r) * 128 + k0 + cc];
                As[r][cc] = v.x; As[r][cc+1] = v.y; As[r][cc+2] = v.z; As[r][cc+3] = v.w;
            }
        }
        {
            int kk = u >> 4, c = (u & 15) * 4;
            #pragma unroll
            for (int h = 0; h < 2; ++h) {
                float4 v = *(const float4*)&W[(size_t)(k0 + kk + h * 16) * 128 + c0 + c];
                *(float4*)&Wt[kk + h * 16][c] = v;
            }
        }
        __syncthreads();
        #pragma unroll
        for (int kk = 0; kk < 32; ++kk) {
            float4 wv = *(const float4*)&Wt[kk][tx * 4];
            float a0 = As[ty * 4 + 0][kk];
            float a1 = As[ty * 4 + 1][kk];
            float a2 = As[ty * 4 + 2][kk];
            float a3 = As[ty * 4 + 3][kk];
            acc0.x += a0 * wv.x; acc0.y += a0 * wv.y; acc0.z += a0 * wv.z; acc0.w += a0 * wv.w;
            acc1.x += a1 * wv.x; acc1.y += a1 * wv.y; acc1.z += a1 * wv.z; acc1.w += a1 * wv.w;
            acc2.x += a2 * wv.x; acc2.y += a2 * wv.y; acc2.z += a2 * wv.z; acc2.w += a2 * wv.w;
            acc3.x += a3 * wv.x; acc3.y += a3 * wv.y; acc3.z += a3 * wv.z; acc3.w += a3 * wv.w;
        }
    }
    int r = r0 + ty * 4;
    if (r + 0 < n) *(float4*)&C[(size_t)(r + 0) * 128 + c0 + tx * 4] = acc0;
    if (r + 1 < n) *(float4*)&C[(size_t)(r + 1) * 128 + c0 + tx * 4] = acc1;
    if (r + 2 < n) *(float4*)&C[(size_t)(r + 2) * 128 + c0 + tx * 4] = acc2;
    if (r + 3 < n) *(float4*)&C[(size_t)(r + 3) * 128 + c0 + tx * 4] = acc3;
}

// ---------- fused GCN aggregation (stages 2/3): wave-per-node, csr2, XCD-swizzled --
__global__ void gcn_agg_fused2_k(const float* __restrict__ hW, const int2* __restrict__ csr2,
                                 const int* __restrict__ off, const int* __restrict__ cnt,
                                 const float* __restrict__ dis, const float* __restrict__ bias,
                                 const float* __restrict__ Wsc,
                                 float* __restrict__ hout, float* __restrict__ hs,
                                 float* __restrict__ hsd, int n, int cpx) {
    int wg = ((blockIdx.x & 7) * cpx) + (blockIdx.x >> 3);
    int t = wg * blockDim.x + threadIdx.x;
    int i = t >> 6;              // one wave per node
    int lane = threadIdx.x & 63;
    if (i >= n) return;
    const float2* hW2 = (const float2*)hW;
    int s0 = off[i], e0 = s0 + cnt[i];
    float accx = 0.f, accy = 0.f;
    for (int j0 = s0; j0 < e0; j0 += 64) {
        int rem = e0 - j0;
        int m = rem < 64 ? rem : 64;
        int sv = 0; float wv = 0.f;
        if (lane < m) { int2 ec = csr2[j0 + lane]; sv = ec.x; wv = __int_as_float(ec.y); }
        int u = 0;
        for (; u + 4 <= m; u += 4) {
            int a0 = __shfl(sv, u + 0), a1 = __shfl(sv, u + 1);
            int a2 = __shfl(sv, u + 2), a3 = __shfl(sv, u + 3);
            float w0 = __shfl(wv, u + 0), w1 = __shfl(wv, u + 1);
            float w2 = __shfl(wv, u + 2), w3 = __shfl(wv, u + 3);
            float2 v0 = hW2[(size_t)a0 * 64 + lane];
            float2 v1 = hW2[(size_t)a1 * 64 + lane];
            float2 v2 = hW2[(size_t)a2 * 64 + lane];
            float2 v3 = hW2[(size_t)a3 * 64 + lane];
            accx += v0.x * w0 + v1.x * w1 + v2.x * w2 + v3.x * w3;
            accy += v0.y * w0 + v1.y * w1 + v2.y * w2 + v3.y * w3;
        }
        for (; u < m; ++u) {
            int s = __shfl(sv, u);
            float w = __shfl(wv, u);
            float2 v = hW2[(size_t)s * 64 + lane];
            accx += v.x * w; accy += v.y * w;
        }
    }
    float di = dis[i];
    float2 hv = hW2[(size_t)i * 64 + lane];
    float ox = fmaxf(di * accx + hv.x * (di * di) + bias[lane * 2], 0.f);
    float oy = fmaxf(di * accy + hv.y * (di * di) + bias[lane * 2 + 1], 0.f);
    float2 o; o.x = ox; o.y = oy;
    ((float2*)hout)[(size_t)i * 64 + lane] = o;
    float part = ox * Wsc[lane * 2] + oy * Wsc[lane * 2 + 1];
    #pragma unroll
    for (int sh = 32; sh >= 1; sh >>= 1) part += __shfl_xor(part, sh);
    if (lane == 0) { hs[i] = part; hsd[i] = part * di; }
}

// ---- fused: score gather (hsd via LDS) + top-k + newid + pool(tanh) + readout ----
template <int CAP, int K>
__global__ void score_topk_pool_k(const float* __restrict__ hout,
                                  const float* __restrict__ hs, const float* __restrict__ hsd,
                                  const int2* __restrict__ csr2, const int* __restrict__ off,
                                  const int* __restrict__ cnt, const float* __restrict__ dis,
                                  const float* __restrict__ bs,
                                  float* __restrict__ hA, float* __restrict__ z,
                                  int* __restrict__ newid, int cur) {
    __shared__ float v[CAP];
    __shared__ int ix[CAP];
    __shared__ float zm[CAP];
    __shared__ float zs[CAP];
    __shared__ float hl[CAP];
    int b = blockIdx.x, t = threadIdx.x;
    if (t < cur) hl[t] = hsd[b * cur + t];
    __syncthreads();
    // 1) score (GCN with shared CSR/dis), hsd gathered from LDS
    float sc = -INFINITY;
    if (t < cur) {
        int i = b * cur + t;
        int s0 = off[i], e0 = s0 + cnt[i];
        float acc = 0.f;
        int j = s0;
        for (; j + 4 <= e0; j += 4) {
            int x0 = csr2[j].x, x1 = csr2[j+1].x, x2 = csr2[j+2].x, x3 = csr2[j+3].x;
            acc += hl[x0 - b*cur] + hl[x1 - b*cur] + hl[x2 - b*cur] + hl[x3 - b*cur];
        }
        for (; j < e0; ++j) acc += hl[csr2[j].x - b*cur];
        float di = dis[i];
        sc = di * acc + hs[i] * (di * di) + bs[0];
    }
    v[t] = sc; ix[t] = t;
    __syncthreads();
    // 2) bitonic sort (value desc, idx asc)
    for (int size = 2; size <= CAP; size <<= 1) {
        for (int stride = size >> 1; stride > 0; stride >>= 1) {
            if (t < CAP / 2) {
                int pos = 2 * t - (t & (stride - 1));
                int j2 = pos + stride;
                bool asc = (pos & size) == 0;
                float v0 = v[pos], v1 = v[j2];
                int i0 = ix[pos], i1 = ix[j2];
                bool jb = (v1 > v0) || (v1 == v0 && i1 < i0);
                bool sw = asc ? jb : !jb;
                if (sw) { v[pos] = v1; v[j2] = v0; ix[pos] = i1; ix[j2] = i0; }
            }
            __syncthreads();
        }
    }
    // 3) newid for ALL of this graph's old nodes
    if (t < K)            newid[b * cur + ix[t]] = b * K + t;
    else if (ix[t] < cur) newid[b * cur + ix[t]] = -1;
    if (t < K) zm[t] = tanhf(v[t]);
    __syncthreads();
    // 4) pool gather + readout
    if constexpr (CAP >= 128) {
        const int G = CAP / 128;
        int g = t >> 7, f = t & 127;
        float vmax = -INFINITY, vsum = 0.f;
        for (int j = g; j < K; j += G) {
            int src = b * cur + ix[j];
            float val = hout[(size_t)src * 128 + f] * zm[j];
            hA[((size_t)b * K + j) * 128 + f] = val;
            vmax = fmaxf(vmax, val); vsum += val;
        }
        __syncthreads();
        zm[t] = vmax; zs[t] = vsum;
        __syncthreads();
        if (t < 128) {
            float m = zm[t], s2 = zs[t];
            for (int g2 = 1; g2 < G; ++g2) { m = fmaxf(m, zm[g2 * 128 + t]); s2 += zs[g2 * 128 + t]; }
            z[b * 256 + t] += m;
            z[b * 256 + 128 + t] += s2 / (float)K;
        }
    } else {
        float vmax0 = -INFINITY, vsum0 = 0.f, vmax1 = -INFINITY, vsum1 = 0.f;
        for (int j = 0; j < K; ++j) {
            int src = b * cur + ix[j];
            float gt = zm[j];
            float a = hout[(size_t)src * 128 + t] * gt;
            float c = hout[(size_t)src * 128 + 64 + t] * gt;
            hA[((size_t)b * K + j) * 128 + t] = a;
            hA[((size_t)b * K + j) * 128 + 64 + t] = c;
            vmax0 = fmaxf(vmax0, a); vsum0 += a;
            vmax1 = fmaxf(vmax1, c); vsum1 += c;
        }
        z[b * 256 + t] += vmax0;
        z[b * 256 + 64 + t] += vmax1;
        z[b * 256 + 128 + t] += vsum0 / (float)K;
        z[b * 256 + 192 + t] += vsum1 / (float)K;
    }
}

// ---------------- MLP head + log_softmax ----------------
__global__ void mlp_head_k(const float* __restrict__ z,
                           const float* __restrict__ Wl1, const float* __restrict__ bl1,
                           const float* __restrict__ Wl2, const float* __restrict__ bl2,
                           const float* __restrict__ Wl3, const float* __restrict__ bl3,
                           float* __restrict__ out) {
    __shared__ float zr[256], h1[128], h2[64], lg[NCLS], red[2];
    int b = blockIdx.x, t = threadIdx.x;  // 128 threads
    zr[t] = z[b * 256 + t];
    zr[t + 128] = z[b * 256 + 128 + t];
    __syncthreads();
    float acc = bl1[t];
    #pragma unroll 8
    for (int i = 0; i < 256; ++i) acc += zr[i] * Wl1[i * 128 + t];
    h1[t] = fmaxf(acc, 0.f);
    __syncthreads();
    if (t < 64) {
        float a2 = bl2[t];
        #pragma unroll 8
        for (int i = 0; i < 128; ++i) a2 += h1[i] * Wl2[i * 64 + t];
        h2[t] = fmaxf(a2, 0.f);
    }
    __syncthreads();
    if (t < NCLS) {
        float a3 = bl3[t];
        #pragma unroll 8
        for (int i = 0; i < 64; ++i) a3 += h2[i] * Wl3[i * NCLS + t];
        lg[t] = a3;
    }
    __syncthreads();
    if (t == 0) {
        float m = lg[0];
        for (int i = 1; i < NCLS; ++i) m = fmaxf(m, lg[i]);
        float s = 0.f;
        for (int i = 0; i < NCLS; ++i) s += expf(lg[i] - m);
        red[0] = m; red[1] = logf(s);
    }
    __syncthreads();
    if (t < NCLS) out[b * NCLS + t] = lg[t] - red[0] - red[1];
}

// ---------------- host ----------------
extern "C" void kernel_launch(void* const* d_in, const int* in_sizes, int n_in,
                              void* d_out, int out_size, void* d_ws, size_t ws_size,
                              hipStream_t stream) {
    const float* x   = (const float*)d_in[0];
    const int*   ei  = (const int*)d_in[1];
    const float* W1  = (const float*)d_in[2];  const float* b1  = (const float*)d_in[3];
    const float* W2  = (const float*)d_in[4];  const float* b2  = (const float*)d_in[5];
    const float* W3  = (const float*)d_in[6];  const float* b3  = (const float*)d_in[7];
    const float* Ws1 = (const float*)d_in[8];  const float* bs1 = (const float*)d_in[9];
    const float* Ws2 = (const float*)d_in[10]; const float* bs2 = (const float*)d_in[11];
    const float* Ws3 = (const float*)d_in[12]; const float* bs3 = (const float*)d_in[13];
    const float* Wl1 = (const float*)d_in[14]; const float* bl1 = (const float*)d_in[15];
    const float* Wl2 = (const float*)d_in[16]; const float* bl2 = (const float*)d_in[17];
    const float* Wl3 = (const float*)d_in[18]; const float* bl3 = (const float*)d_in[19];
    float* out = (float*)d_out;

    const int NMAX = NB * N0;  // 65536
    const int N1 = NB * KP1;   // 13120
    const int N2 = NB * KP2;   // 2624

    char* p = (char*)d_ws;
    // --- zeroed-once region: cnt0, cnt1, cnt2, gctr, z ---
    int*   cnt0 = (int*)p;   p += (size_t)NMAX * 4;
    int*   cnt1 = (int*)p;   p += (size_t)N1 * 4;
    int*   cnt2 = (int*)p;   p += (size_t)N2 * 4;
    int*   gctr = (int*)p;   p += 8 * 4;   // [0..2]=CSR bases
    float* z    = (float*)p; p += (size_t)NB * 256 * 4;
    size_t zero_bytes = (size_t)(p - (char*)d_ws);
    // --- rest ---
    float* hW     = (float*)p; p += (size_t)N1 * 128 * 4;     // stage2/3 gemm out
    float* hout   = (float*)p; p += (size_t)NMAX * 128 * 4;
    float* hA     = (float*)p; p += (size_t)N1 * 128 * 4;
    float* y      = (float*)p; p += (size_t)NMAX * FIN * 4;
    float* dis    = (float*)p; p += (size_t)NMAX * 4;
    float* hs     = (float*)p; p += (size_t)NMAX * 4;
    float* hsd    = (float*)p; p += (size_t)NMAX * 4;
    int* newid    = (int*)p;   p += (size_t)NMAX * 4;
    int* off      = (int*)p;   p += (size_t)NMAX * 4;
    int* cursor   = (int*)p;   p += (size_t)NMAX * 4;
    int2* ebuf    = (int2*)p;  p += (size_t)NEDGE * 8;
    int2* ebuf2   = (int2*)p;  p += (size_t)NEDGE * 8;
    int2* csr2    = (int2*)p;  p += (size_t)NEDGE * 8;

    const int EB = ceil_div(NEDGE, 256);

    hipMemsetAsync(d_ws, 0, zero_bytes, stream);
    count1_k<<<EB, 256, 0, stream>>>(ei, cnt0);

    // ---------------- stage 1 ----------------
    offsets_k<<<NMAX / 256, 256, 0, stream>>>(cnt0, off, cursor, dis, gctr + 0, NMAX);
    scatter1_k<<<EB, 256, 0, stream>>>(ei, cursor, dis, csr2);
    agg10_k<<<NB * 4, 256, 0, stream>>>(x, csr2, off, cnt0, dis, y);
    gemm_fin_fused_k<<<NMAX / 4, 256, 0, stream>>>(y, W1, b1, Ws1, dis, hout, hs, hsd, NMAX);
    score_topk_pool_k<1024, KP1><<<NB, 1024, 0, stream>>>(
        hout, hs, hsd, csr2, off, cnt0, dis, bs1, hA, z, newid, N0);
    edge_update1_k<<<EB, 256, 0, stream>>>(ei, newid, ebuf, cnt1);

    // ---------------- stage 2 ----------------
    {
        dim3 g(ceil_div(N1, 64), 2);
        gemm128_tiled_k<<<g, 256, 0, stream>>>(hA, W2, hW, N1);
    }
    offsets_k<<<ceil_div(N1, 256), 256, 0, stream>>>(cnt1, off, cursor, dis, gctr + 1, N1);
    scatter_k<<<EB, 256, 0, stream>>>(ebuf, cursor, dis, csr2);
    gcn_agg_fused2_k<<<N1 / 4, 256, 0, stream>>>(
        hW, csr2, off, cnt1, dis, b2, Ws2, hout, hs, hsd, N1, N1 / 32);
    score_topk_pool_k<256, KP2><<<NB, 256, 0, stream>>>(
        hout, hs, hsd, csr2, off, cnt1, dis, bs2, hA, z, newid, KP1);
    edge_update2_k<<<EB, 256, 0, stream>>>(ebuf, newid, ebuf2, cnt2);

    // ---------------- stage 3 ----------------
    {
        dim3 g(ceil_div(N2, 64), 2);
        gemm128_tiled_k<<<g, 256, 0, stream>>>(hA, W3, hW, N2);
    }
    offsets_k<<<ceil_div(N2, 256), 256, 0, stream>>>(cnt2, off, cursor, dis, gctr + 2, N2);
    scatter_k<<<EB, 256, 0, stream>>>(ebuf2, cursor, dis, csr2);
    gcn_agg_fused2_k<<<N2 / 4, 256, 0, stream>>>(
        hW, csr2, off, cnt2, dis, b3, Ws3, hout, hs, hsd, N2, N2 / 32);
    score_topk_pool_k<64, KP3><<<NB, 64, 0, stream>>>(
        hout, hs, hsd, csr2, off, cnt2, dis, bs3, hA, z, newid, KP2);

    mlp_head_k<<<NB, 128, 0, stream>>>(z, Wl1, bl1, Wl2, bl2, Wl3, bl3, out);
}

// Round 12
// 296.999 us; speedup vs baseline: 1.7780x; 1.1647x over previous
//
#include <hip/hip_runtime.h>
#include <math.h>

#define NB 64          // graphs
#define N0 1024        // nodes per graph (stage 1)
#define NEDGE 1048576  // total edges
#define EPG 16384      // edges per graph (NEDGE/NB) — input edges are graph-grouped
#define FIN 10
#define NCLS 10
#define KP1 205
#define KP2 41
#define KP3 9

static inline int ceil_div(int a, int b) { return (a + b - 1) / b; }

// ======== stage-1 CSR build: one block per graph, all-LDS (no global atomics) =====
// csr2[b*EPG + pos] = {src_global, dis[src]}, off/cnt/dis written per node.
__global__ __launch_bounds__(1024) void build_csr1_k(const int* __restrict__ ei,
                                                     float* __restrict__ disg,
                                                     int* __restrict__ offg,
                                                     int* __restrict__ cntg,
                                                     int2* __restrict__ csr2) {
    __shared__ int cnt[N0];
    __shared__ int cur[N0];
    __shared__ float disl[N0];
    __shared__ int scan[1024];
    int b = blockIdx.x, t = threadIdx.x;
    cnt[t] = 0;
    __syncthreads();
    const int ebase = b * EPG;
    const int nbase = b * N0;
    #pragma unroll
    for (int u = 0; u < EPG / 1024; ++u) {
        int d = ei[NEDGE + ebase + u * 1024 + t] - nbase;
        atomicAdd(&cnt[d], 1);
    }
    __syncthreads();
    int v = cnt[t];
    scan[t] = v;
    __syncthreads();
    #pragma unroll
    for (int s = 1; s < 1024; s <<= 1) {
        int tv = (t >= s) ? scan[t - s] : 0;
        __syncthreads();
        scan[t] += tv;
        __syncthreads();
    }
    int excl = scan[t] - v;
    cur[t] = excl;
    float di = rsqrtf((float)v + 1.0f);
    disl[t] = di;
    offg[nbase + t] = ebase + excl;
    cntg[nbase + t] = v;
    disg[nbase + t] = di;
    __syncthreads();
    #pragma unroll
    for (int u = 0; u < EPG / 1024; ++u) {
        int j = ebase + u * 1024 + t;
        int s = ei[j], d = ei[NEDGE + j] - nbase;
        int pos = atomicAdd(&cur[d], 1);
        int2 o; o.x = s; o.y = __float_as_int(disl[s - nbase]);
        csr2[ebase + pos] = o;
    }
}

// ======== stage-2/3 CSR build: remap ORIGINAL edges via LDS newid slices ==========
// COMPOSE=false: node l -> nid1[b*N0+l] (stage-2 id). COMPOSE=true: additionally
// through nid2 (stage-2 id -> stage-3 id). Dead edges dropped. No global atomics.
template <int CUR, int PREVK, bool COMPOSE>
__global__ __launch_bounds__(1024) void build_csrN_k(const int* __restrict__ ei,
                                                     const int* __restrict__ nid1,
                                                     const int* __restrict__ nid2,
                                                     float* __restrict__ disg,
                                                     int* __restrict__ offg,
                                                     int* __restrict__ cntg,
                                                     int2* __restrict__ csr2) {
    __shared__ int n1[N0];
    __shared__ int n2c[COMPOSE ? PREVK : 1];
    __shared__ int cnt[CUR];
    __shared__ int cur[CUR];
    __shared__ float disl[CUR];
    __shared__ int scan[1024];
    int b = blockIdx.x, t = threadIdx.x;
    n1[t] = nid1[b * N0 + t];
    if (COMPOSE && t < PREVK) n2c[t] = nid2[b * PREVK + t];
    if (t < CUR) cnt[t] = 0;
    __syncthreads();
    const int ebase = b * EPG;
    const int nbase = b * N0;
    auto mapn = [&](int l) -> int {   // orig-local -> new-local or -1
        int g1 = n1[l];
        if (g1 < 0) return -1;
        if (!COMPOSE) return g1 - b * CUR;
        int g2 = n2c[g1 - b * PREVK];
        return (g2 < 0) ? -1 : (g2 - b * CUR);
    };
    #pragma unroll
    for (int u = 0; u < EPG / 1024; ++u) {
        int j = ebase + u * 1024 + t;
        int s = ei[j] - nbase, d = ei[NEDGE + j] - nbase;
        int ld = mapn(d);
        if (ld < 0) continue;
        if (mapn(s) < 0) continue;
        atomicAdd(&cnt[ld], 1);
    }
    __syncthreads();
    int v = (t < CUR) ? cnt[t] : 0;
    scan[t] = v;
    __syncthreads();
    #pragma unroll
    for (int s = 1; s < 1024; s <<= 1) {
        int tv = (t >= s) ? scan[t - s] : 0;
        __syncthreads();
        scan[t] += tv;
        __syncthreads();
    }
    if (t < CUR) {
        int excl = scan[t] - v;
        cur[t] = excl;
        float di = rsqrtf((float)v + 1.0f);
        disl[t] = di;
        offg[b * CUR + t] = ebase + excl;
        cntg[b * CUR + t] = v;
        disg[b * CUR + t] = di;
    }
    __syncthreads();
    #pragma unroll
    for (int u = 0; u < EPG / 1024; ++u) {
        int j = ebase + u * 1024 + t;
        int s = ei[j] - nbase, d = ei[NEDGE + j] - nbase;
        int ld = mapn(d);
        if (ld < 0) continue;
        int ls = mapn(s);
        if (ls < 0) continue;
        int pos = atomicAdd(&cur[ld], 1);
        int2 o; o.x = b * CUR + ls; o.y = __float_as_int(disl[ls]);
        csr2[ebase + pos] = o;
    }
}

// ---------------- stage-1: aggregate RAW x (10-dim) pre-GEMM, LDS-staged graph ----
__global__ __launch_bounds__(256) void agg10_k(const float* __restrict__ x,
                                               const int2* __restrict__ csr2,
                                               const int* __restrict__ off,
                                               const int* __restrict__ cnt,
                                               const float* __restrict__ dis,
                                               float* __restrict__ y) {
    __shared__ float xl[N0 * 11];  // rows padded to 11 floats (bank spread)
    int b = blockIdx.x >> 2, chunk = blockIdx.x & 3;
    const float* xg = x + (size_t)b * (N0 * FIN);
    for (int u = threadIdx.x; u < N0 * FIN; u += 256) {
        int r = u / FIN, c = u - r * FIN;
        xl[r * 11 + c] = xg[u];
    }
    __syncthreads();
    int li = chunk * 256 + threadIdx.x;
    int i  = b * N0 + li;
    int s0 = off[i], m = cnt[i];
    int base = b * N0;
    float acc[FIN];
    #pragma unroll
    for (int f = 0; f < FIN; ++f) acc[f] = 0.f;
    int j = 0;
    for (; j + 2 <= m; j += 2) {
        int2 e0 = csr2[s0 + j], e1 = csr2[s0 + j + 1];
        int sl0 = (e0.x - base) * 11, sl1 = (e1.x - base) * 11;
        float w0 = __int_as_float(e0.y), w1 = __int_as_float(e1.y);
        #pragma unroll
        for (int f = 0; f < FIN; ++f) acc[f] += xl[sl0 + f] * w0 + xl[sl1 + f] * w1;
    }
    if (j < m) {
        int2 e0 = csr2[s0 + j];
        int sl0 = (e0.x - base) * 11;
        float w0 = __int_as_float(e0.y);
        #pragma unroll
        for (int f = 0; f < FIN; ++f) acc[f] += xl[sl0 + f] * w0;
    }
    float di = dis[i], d2 = di * di;
    #pragma unroll
    for (int f = 0; f < FIN; ++f)
        y[(size_t)i * FIN + f] = di * acc[f] + d2 * xl[li * 11 + f];
}

// ---------------- fused: hout = relu(y@W + b); hs = hout@Wsc; hsd = hs*dis -------
__global__ void gemm_fin_fused_k(const float* __restrict__ y, const float* __restrict__ W,
                                 const float* __restrict__ bb, const float* __restrict__ Wsc,
                                 const float* __restrict__ dis,
                                 float* __restrict__ hout, float* __restrict__ hs,
                                 float* __restrict__ hsd, int n) {
    __shared__ float Ws[FIN * 128];
    __shared__ float Sc[128];
    for (int u = threadIdx.x; u < FIN * 128; u += 256) Ws[u] = W[u];
    if (threadIdx.x < 128) Sc[threadIdx.x] = Wsc[threadIdx.x];
    __syncthreads();
    int t = blockIdx.x * 256 + threadIdx.x;
    int i = t >> 6, lane = threadIdx.x & 63;
    if (i >= n) return;
    float a = (lane < FIN) ? y[(size_t)i * FIN + lane] : 0.f;
    const float2* W2 = (const float2*)Ws;
    float ax = bb[lane * 2], ay = bb[lane * 2 + 1];
    #pragma unroll
    for (int k = 0; k < FIN; ++k) {
        float ak = __shfl(a, k);
        float2 w = W2[k * 64 + lane];
        ax += ak * w.x; ay += ak * w.y;
    }
    ax = fmaxf(ax, 0.f); ay = fmaxf(ay, 0.f);
    float2 o; o.x = ax; o.y = ay;
    ((float2*)hout)[(size_t)i * 64 + lane] = o;
    float part = ax * Sc[lane * 2] + ay * Sc[lane * 2 + 1];
    #pragma unroll
    for (int sh = 32; sh >= 1; sh >>= 1) part += __shfl_xor(part, sh);
    if (lane == 0) { hs[i] = part; hsd[i] = part * dis[i]; }
}

// ---------------- GEMM (K=128): 64x64 tile, 4x4 per thread, register-tiled -----
__global__ __launch_bounds__(256) void gemm128_tiled_k(const float* __restrict__ A,
                                                       const float* __restrict__ W,
                                                       float* __restrict__ C, int n) {
    __shared__ float As[64][33];
    __shared__ float Wt[32][64];
    int tx = threadIdx.x & 15, ty = threadIdx.x >> 4;
    int r0 = blockIdx.x * 64;
    int c0 = blockIdx.y * 64;
    float4 acc0 = {0,0,0,0}, acc1 = {0,0,0,0}, acc2 = {0,0,0,0}, acc3 = {0,0,0,0};
    int u = threadIdx.x;
    for (int k0 = 0; k0 < 128; k0 += 32) {
        __syncthreads();
        {
            int rr = u >> 3, cc = (u & 7) * 4;
            #pragma unroll
            for (int h = 0; h < 2; ++h) {
                int r = rr + h * 32;
                float4 v = {0,0,0,0};
                if (r0 + r < n) v = *(const float4*)&A[(size_t)(r0 + r) * 128 + k0 + cc];
                As[r][cc] = v.x; As[r][cc+1] = v.y; As[r][cc+2] = v.z; As[r][cc+3] = v.w;
            }
        }
        {
            int kk = u >> 4, c = (u & 15) * 4;
            #pragma unroll
            for (int h = 0; h < 2; ++h) {
                float4 v = *(const float4*)&W[(size_t)(k0 + kk + h * 16) * 128 + c0 + c];
                *(float4*)&Wt[kk + h * 16][c] = v;
            }
        }
        __syncthreads();
        #pragma unroll
        for (int kk = 0; kk < 32; ++kk) {
            float4 wv = *(const float4*)&Wt[kk][tx * 4];
            float a0 = As[ty * 4 + 0][kk];
            float a1 = As[ty * 4 + 1][kk];
            float a2 = As[ty * 4 + 2][kk];
            float a3 = As[ty * 4 + 3][kk];
            acc0.x += a0 * wv.x; acc0.y += a0 * wv.y; acc0.z += a0 * wv.z; acc0.w += a0 * wv.w;
            acc1.x += a1 * wv.x; acc1.y += a1 * wv.y; acc1.z += a1 * wv.z; acc1.w += a1 * wv.w;
            acc2.x += a2 * wv.x; acc2.y += a2 * wv.y; acc2.z += a2 * wv.z; acc2.w += a2 * wv.w;
            acc3.x += a3 * wv.x; acc3.y += a3 * wv.y; acc3.z += a3 * wv.z; acc3.w += a3 * wv.w;
        }
    }
    int r = r0 + ty * 4;
    if (r + 0 < n) *(float4*)&C[(size_t)(r + 0) * 128 + c0 + tx * 4] = acc0;
    if (r + 1 < n) *(float4*)&C[(size_t)(r + 1) * 128 + c0 + tx * 4] = acc1;
    if (r + 2 < n) *(float4*)&C[(size_t)(r + 2) * 128 + c0 + tx * 4] = acc2;
    if (r + 3 < n) *(float4*)&C[(size_t)(r + 3) * 128 + c0 + tx * 4] = acc3;
}

// ---------- fused GCN aggregation (stages 2/3): wave-per-node, csr2, XCD-swizzled --
__global__ void gcn_agg_fused2_k(const float* __restrict__ hW, const int2* __restrict__ csr2,
                                 const int* __restrict__ off, const int* __restrict__ cnt,
                                 const float* __restrict__ dis, const float* __restrict__ bias,
                                 const float* __restrict__ Wsc,
                                 float* __restrict__ hout, float* __restrict__ hs,
                                 float* __restrict__ hsd, int n, int cpx) {
    int wg = ((blockIdx.x & 7) * cpx) + (blockIdx.x >> 3);
    int t = wg * blockDim.x + threadIdx.x;
    int i = t >> 6;              // one wave per node
    int lane = threadIdx.x & 63;
    if (i >= n) return;
    const float2* hW2 = (const float2*)hW;
    int s0 = off[i], e0 = s0 + cnt[i];
    float accx = 0.f, accy = 0.f;
    for (int j0 = s0; j0 < e0; j0 += 64) {
        int rem = e0 - j0;
        int m = rem < 64 ? rem : 64;
        int sv = 0; float wv = 0.f;
        if (lane < m) { int2 ec = csr2[j0 + lane]; sv = ec.x; wv = __int_as_float(ec.y); }
        int u = 0;
        for (; u + 4 <= m; u += 4) {
            int a0 = __shfl(sv, u + 0), a1 = __shfl(sv, u + 1);
            int a2 = __shfl(sv, u + 2), a3 = __shfl(sv, u + 3);
            float w0 = __shfl(wv, u + 0), w1 = __shfl(wv, u + 1);
            float w2 = __shfl(wv, u + 2), w3 = __shfl(wv, u + 3);
            float2 v0 = hW2[(size_t)a0 * 64 + lane];
            float2 v1 = hW2[(size_t)a1 * 64 + lane];
            float2 v2 = hW2[(size_t)a2 * 64 + lane];
            float2 v3 = hW2[(size_t)a3 * 64 + lane];
            accx += v0.x * w0 + v1.x * w1 + v2.x * w2 + v3.x * w3;
            accy += v0.y * w0 + v1.y * w1 + v2.y * w2 + v3.y * w3;
        }
        for (; u < m; ++u) {
            int s = __shfl(sv, u);
            float w = __shfl(wv, u);
            float2 v = hW2[(size_t)s * 64 + lane];
            accx += v.x * w; accy += v.y * w;
        }
    }
    float di = dis[i];
    float2 hv = hW2[(size_t)i * 64 + lane];
    float ox = fmaxf(di * accx + hv.x * (di * di) + bias[lane * 2], 0.f);
    float oy = fmaxf(di * accy + hv.y * (di * di) + bias[lane * 2 + 1], 0.f);
    float2 o; o.x = ox; o.y = oy;
    ((float2*)hout)[(size_t)i * 64 + lane] = o;
    float part = ox * Wsc[lane * 2] + oy * Wsc[lane * 2 + 1];
    #pragma unroll
    for (int sh = 32; sh >= 1; sh >>= 1) part += __shfl_xor(part, sh);
    if (lane == 0) { hs[i] = part; hsd[i] = part * di; }
}

// ---- fused: score gather (hsd via LDS) + top-k + newid + pool(tanh) + readout ----
template <int CAP, int K>
__global__ void score_topk_pool_k(const float* __restrict__ hout,
                                  const float* __restrict__ hs, const float* __restrict__ hsd,
                                  const int2* __restrict__ csr2, const int* __restrict__ off,
                                  const int* __restrict__ cnt, const float* __restrict__ dis,
                                  const float* __restrict__ bs,
                                  float* __restrict__ hA, float* __restrict__ z,
                                  int* __restrict__ newid, int cur) {
    __shared__ float v[CAP];
    __shared__ int ix[CAP];
    __shared__ float zm[CAP];
    __shared__ float zs[CAP];
    __shared__ float hl[CAP];
    int b = blockIdx.x, t = threadIdx.x;
    if (t < cur) hl[t] = hsd[b * cur + t];
    __syncthreads();
    // 1) score (GCN with shared CSR/dis), hsd gathered from LDS
    float sc = -INFINITY;
    if (t < cur) {
        int i = b * cur + t;
        int s0 = off[i], e0 = s0 + cnt[i];
        float acc = 0.f;
        int j = s0;
        for (; j + 4 <= e0; j += 4) {
            int x0 = csr2[j].x, x1 = csr2[j+1].x, x2 = csr2[j+2].x, x3 = csr2[j+3].x;
            acc += hl[x0 - b*cur] + hl[x1 - b*cur] + hl[x2 - b*cur] + hl[x3 - b*cur];
        }
        for (; j < e0; ++j) acc += hl[csr2[j].x - b*cur];
        float di = dis[i];
        sc = di * acc + hs[i] * (di * di) + bs[0];
    }
    v[t] = sc; ix[t] = t;
    __syncthreads();
    // 2) bitonic sort (value desc, idx asc)
    for (int size = 2; size <= CAP; size <<= 1) {
        for (int stride = size >> 1; stride > 0; stride >>= 1) {
            if (t < CAP / 2) {
                int pos = 2 * t - (t & (stride - 1));
                int j2 = pos + stride;
                bool asc = (pos & size) == 0;
                float v0 = v[pos], v1 = v[j2];
                int i0 = ix[pos], i1 = ix[j2];
                bool jb = (v1 > v0) || (v1 == v0 && i1 < i0);
                bool sw = asc ? jb : !jb;
                if (sw) { v[pos] = v1; v[j2] = v0; ix[pos] = i1; ix[j2] = i0; }
            }
            __syncthreads();
        }
    }
    // 3) newid for ALL of this graph's old nodes
    if (t < K)            newid[b * cur + ix[t]] = b * K + t;
    else if (ix[t] < cur) newid[b * cur + ix[t]] = -1;
    if (t < K) zm[t] = tanhf(v[t]);
    __syncthreads();
    // 4) pool gather + readout
    if constexpr (CAP >= 128) {
        const int G = CAP / 128;
        int g = t >> 7, f = t & 127;
        float vmax = -INFINITY, vsum = 0.f;
        for (int j = g; j < K; j += G) {
            int src = b * cur + ix[j];
            float val = hout[(size_t)src * 128 + f] * zm[j];
            hA[((size_t)b * K + j) * 128 + f] = val;
            vmax = fmaxf(vmax, val); vsum += val;
        }
        __syncthreads();
        zm[t] = vmax; zs[t] = vsum;
        __syncthreads();
        if (t < 128) {
            float m = zm[t], s2 = zs[t];
            for (int g2 = 1; g2 < G; ++g2) { m = fmaxf(m, zm[g2 * 128 + t]); s2 += zs[g2 * 128 + t]; }
            z[b * 256 + t] += m;
            z[b * 256 + 128 + t] += s2 / (float)K;
        }
    } else {
        float vmax0 = -INFINITY, vsum0 = 0.f, vmax1 = -INFINITY, vsum1 = 0.f;
        for (int j = 0; j < K; ++j) {
            int src = b * cur + ix[j];
            float gt = zm[j];
            float a = hout[(size_t)src * 128 + t] * gt;
            float c = hout[(size_t)src * 128 + 64 + t] * gt;
            hA[((size_t)b * K + j) * 128 + t] = a;
            hA[((size_t)b * K + j) * 128 + 64 + t] = c;
            vmax0 = fmaxf(vmax0, a); vsum0 += a;
            vmax1 = fmaxf(vmax1, c); vsum1 += c;
        }
        z[b * 256 + t] += vmax0;
        z[b * 256 + 64 + t] += vmax1;
        z[b * 256 + 128 + t] += vsum0 / (float)K;
        z[b * 256 + 192 + t] += vsum1 / (float)K;
    }
}

// ---------------- MLP head + log_softmax ----------------
__global__ void mlp_head_k(const float* __restrict__ z,
                           const float* __restrict__ Wl1, const float* __restrict__ bl1,
                           const float* __restrict__ Wl2, const float* __restrict__ bl2,
                           const float* __restrict__ Wl3, const float* __restrict__ bl3,
                           float* __restrict__ out) {
    __shared__ float zr[256], h1[128], h2[64], lg[NCLS], red[2];
    int b = blockIdx.x, t = threadIdx.x;  // 128 threads
    zr[t] = z[b * 256 + t];
    zr[t + 128] = z[b * 256 + 128 + t];
    __syncthreads();
    float acc = bl1[t];
    #pragma unroll 8
    for (int i = 0; i < 256; ++i) acc += zr[i] * Wl1[i * 128 + t];
    h1[t] = fmaxf(acc, 0.f);
    __syncthreads();
    if (t < 64) {
        float a2 = bl2[t];
        #pragma unroll 8
        for (int i = 0; i < 128; ++i) a2 += h1[i] * Wl2[i * 64 + t];
        h2[t] = fmaxf(a2, 0.f);
    }
    __syncthreads();
    if (t < NCLS) {
        float a3 = bl3[t];
        #pragma unroll 8
        for (int i = 0; i < 64; ++i) a3 += h2[i] * Wl3[i * NCLS + t];
        lg[t] = a3;
    }
    __syncthreads();
    if (t == 0) {
        float m = lg[0];
        for (int i = 1; i < NCLS; ++i) m = fmaxf(m, lg[i]);
        float s = 0.f;
        for (int i = 0; i < NCLS; ++i) s += expf(lg[i] - m);
        red[0] = m; red[1] = logf(s);
    }
    __syncthreads();
    if (t < NCLS) out[b * NCLS + t] = lg[t] - red[0] - red[1];
}

// ---------------- host ----------------
extern "C" void kernel_launch(void* const* d_in, const int* in_sizes, int n_in,
                              void* d_out, int out_size, void* d_ws, size_t ws_size,
                              hipStream_t stream) {
    const float* x   = (const float*)d_in[0];
    const int*   ei  = (const int*)d_in[1];
    const float* W1  = (const float*)d_in[2];  const float* b1  = (const float*)d_in[3];
    const float* W2  = (const float*)d_in[4];  const float* b2  = (const float*)d_in[5];
    const float* W3  = (const float*)d_in[6];  const float* b3  = (const float*)d_in[7];
    const float* Ws1 = (const float*)d_in[8];  const float* bs1 = (const float*)d_in[9];
    const float* Ws2 = (const float*)d_in[10]; const float* bs2 = (const float*)d_in[11];
    const float* Ws3 = (const float*)d_in[12]; const float* bs3 = (const float*)d_in[13];
    const float* Wl1 = (const float*)d_in[14]; const float* bl1 = (const float*)d_in[15];
    const float* Wl2 = (const float*)d_in[16]; const float* bl2 = (const float*)d_in[17];
    const float* Wl3 = (const float*)d_in[18]; const float* bl3 = (const float*)d_in[19];
    float* out = (float*)d_out;

    const int NMAX = NB * N0;  // 65536
    const int N1 = NB * KP1;   // 13120
    const int N2 = NB * KP2;   // 2624

    char* p = (char*)d_ws;
    float* z      = (float*)p; p += (size_t)NB * 256 * 4;   // zeroed each call
    float* hW     = (float*)p; p += (size_t)N1 * 128 * 4;   // stage2/3 gemm out
    float* hout   = (float*)p; p += (size_t)NMAX * 128 * 4;
    float* hA     = (float*)p; p += (size_t)N1 * 128 * 4;
    float* y      = (float*)p; p += (size_t)NMAX * FIN * 4;
    float* dis    = (float*)p; p += (size_t)NMAX * 4;
    float* hs     = (float*)p; p += (size_t)NMAX * 4;
    float* hsd    = (float*)p; p += (size_t)NMAX * 4;
    int* newid1   = (int*)p;   p += (size_t)NMAX * 4;
    int* newid2   = (int*)p;   p += (size_t)N1 * 4;
    int* off      = (int*)p;   p += (size_t)NMAX * 4;
    int* cnt      = (int*)p;   p += (size_t)NMAX * 4;
    int2* csr2    = (int2*)p;  p += (size_t)NEDGE * 8;

    hipMemsetAsync(z, 0, (size_t)NB * 256 * 4, stream);

    // ---------------- stage 1 ----------------
    build_csr1_k<<<NB, 1024, 0, stream>>>(ei, dis, off, cnt, csr2);
    agg10_k<<<NB * 4, 256, 0, stream>>>(x, csr2, off, cnt, dis, y);
    gemm_fin_fused_k<<<NMAX / 4, 256, 0, stream>>>(y, W1, b1, Ws1, dis, hout, hs, hsd, NMAX);
    score_topk_pool_k<1024, KP1><<<NB, 1024, 0, stream>>>(
        hout, hs, hsd, csr2, off, cnt, dis, bs1, hA, z, newid1, N0);

    // ---------------- stage 2 ----------------
    build_csrN_k<KP1, KP1, false><<<NB, 1024, 0, stream>>>(ei, newid1, nullptr, dis, off, cnt, csr2);
    {
        dim3 g(ceil_div(N1, 64), 2);
        gemm128_tiled_k<<<g, 256, 0, stream>>>(hA, W2, hW, N1);
    }
    gcn_agg_fused2_k<<<N1 / 4, 256, 0, stream>>>(
        hW, csr2, off, cnt, dis, b2, Ws2, hout, hs, hsd, N1, N1 / 32);
    score_topk_pool_k<256, KP2><<<NB, 256, 0, stream>>>(
        hout, hs, hsd, csr2, off, cnt, dis, bs2, hA, z, newid2, KP1);

    // ---------------- stage 3 ----------------
    build_csrN_k<KP2, KP1, true><<<NB, 1024, 0, stream>>>(ei, newid1, newid2, dis, off, cnt, csr2);
    {
        dim3 g(ceil_div(N2, 64), 2);
        gemm128_tiled_k<<<g, 256, 0, stream>>>(hA, W3, hW, N2);
    }
    gcn_agg_fused2_k<<<N2 / 4, 256, 0, stream>>>(
        hW, csr2, off, cnt, dis, b3, Ws3, hout, hs, hsd, N2, N2 / 32);
    score_topk_pool_k<64, KP3><<<NB, 64, 0, stream>>>(
        hout, hs, hsd, csr2, off, cnt, dis, bs3, hA, z, newid1, KP2);

    mlp_head_k<<<NB, 128, 0, stream>>>(z, Wl1, bl1, Wl2, bl2, Wl3, bl3, out);
}